// Round 1
// baseline (656.780 us; speedup 1.0000x reference)
//
#include <hip/hip_runtime.h>

#define NN 50000
#define NE 800000
#define CIN 256
#define HH 64

// ---------------- in-linear: h = x @ W_in + b_in ; hidden = h * temp[0] -----
// One wave (64 threads) per 4 nodes. Thread j computes output channel j for
// 4 nodes. x rows staged in LDS (broadcast reads, conflict-free); W reads are
// 256B coalesced per wave-instr and L1/L2 resident (64 KB total).
__global__ __launch_bounds__(64) void k_in_linear(
    const float* __restrict__ x, const float* __restrict__ W,
    const float* __restrict__ b, const float* __restrict__ temp,
    float* __restrict__ h, float* __restrict__ hidden)
{
    __shared__ float xs[4][CIN];
    const int n0 = blockIdx.x * 4;
    const int j = threadIdx.x;
    #pragma unroll
    for (int r = 0; r < 4; ++r) {
        ((float4*)&xs[r][0])[j] = ((const float4*)(x + (size_t)(n0 + r) * CIN))[j];
    }
    __syncthreads();
    const float bj = b[j];
    float a0 = bj, a1 = bj, a2 = bj, a3 = bj;
    #pragma unroll 8
    for (int k = 0; k < CIN; ++k) {
        const float w = W[k * HH + j];
        a0 = fmaf(xs[0][k], w, a0);
        a1 = fmaf(xs[1][k], w, a1);
        a2 = fmaf(xs[2][k], w, a2);
        a3 = fmaf(xs[3][k], w, a3);
    }
    const float t0 = temp[0];
    const size_t o = (size_t)n0 * HH + j;
    h[o]        = a0;  hidden[o]        = a0 * t0;
    h[o + HH]   = a1;  hidden[o + HH]   = a1 * t0;
    h[o + 2*HH] = a2;  hidden[o + 2*HH] = a2 * t0;
    h[o + 3*HH] = a3;  hidden[o + 3*HH] = a3 * t0;
}

// ---------------- hidden linear: out = act(in) @ W + b ---------------------
// Same decomposition, K = 64. RELU_IN applies relu on the INPUT read
// (cur = relu(agg) from the previous propagation step).
template<bool RELU_IN>
__global__ __launch_bounds__(64) void k_hid_linear(
    const float* __restrict__ in, const float* __restrict__ W,
    const float* __restrict__ b, float* __restrict__ out)
{
    __shared__ float cs[4][HH];
    const int n0 = blockIdx.x * 4;
    const int j = threadIdx.x;
    #pragma unroll
    for (int r = 0; r < 4; ++r) {
        float v = in[(size_t)(n0 + r) * HH + j];
        if (RELU_IN) v = fmaxf(v, 0.0f);
        cs[r][j] = v;
    }
    __syncthreads();
    const float bj = b[j];
    float a0 = bj, a1 = bj, a2 = bj, a3 = bj;
    #pragma unroll 8
    for (int k = 0; k < HH; ++k) {
        const float w = W[k * HH + j];
        a0 = fmaf(cs[0][k], w, a0);
        a1 = fmaf(cs[1][k], w, a1);
        a2 = fmaf(cs[2][k], w, a2);
        a3 = fmaf(cs[3][k], w, a3);
    }
    const size_t o = (size_t)n0 * HH + j;
    out[o]        = a0;
    out[o + HH]   = a1;
    out[o + 2*HH] = a2;
    out[o + 3*HH] = a3;
}

// ---------------- scatter: agg[dst] += z[src] * ew --------------------------
// One thread per (edge, channel): 64 consecutive threads share an edge, so
// the z[src] read is a 256B coalesced wave access and the atomics for one
// edge span one 256B row.
__global__ __launch_bounds__(256) void k_scatter(
    const int* __restrict__ src, const int* __restrict__ dst,
    const float* __restrict__ ew, const float* __restrict__ z,
    float* __restrict__ agg)
{
    const int tid = blockIdx.x * 256 + threadIdx.x;
    const int e = tid >> 6;
    const int j = tid & 63;
    if (e < NE) {
        const float v = z[(size_t)src[e] * HH + j] * ew[e];
        atomicAdd(&agg[(size_t)dst[e] * HH + j], v);
    }
}

// ---------------- accumulate: hidden += relu(agg) * temp[tidx] --------------
__global__ __launch_bounds__(256) void k_accum(
    const float* __restrict__ agg, float* __restrict__ hidden,
    const float* __restrict__ temp, int tidx)
{
    const int i = blockIdx.x * 256 + threadIdx.x;   // float4 index; exact grid
    const float t = temp[tidx];
    float4 a = ((const float4*)agg)[i];
    float4 hd = ((float4*)hidden)[i];
    hd.x += fmaxf(a.x, 0.0f) * t;
    hd.y += fmaxf(a.y, 0.0f) * t;
    hd.z += fmaxf(a.z, 0.0f) * t;
    hd.w += fmaxf(a.w, 0.0f) * t;
    ((float4*)hidden)[i] = hd;
}

extern "C" void kernel_launch(void* const* d_in, const int* in_sizes, int n_in,
                              void* d_out, int out_size, void* d_ws, size_t ws_size,
                              hipStream_t stream)
{
    const float* x     = (const float*)d_in[0];
    const int*   ei    = (const int*)d_in[1];
    const float* ew    = (const float*)d_in[2];
    const float* W_in  = (const float*)d_in[3];
    const float* b_in  = (const float*)d_in[4];
    const float* LW    = (const float*)d_in[5];
    const float* Lb    = (const float*)d_in[6];
    const float* W_out = (const float*)d_in[7];
    const float* b_out = (const float*)d_in[8];
    const float* temp  = (const float*)d_in[9];
    const int* src = ei;            // edge_index[0]
    const int* dst = ei + NE;       // edge_index[1]

    float* ws     = (float*)d_ws;
    float* h      = ws;                           // NN*HH
    float* hidden = h      + (size_t)NN * HH;     // NN*HH
    float* z      = hidden + (size_t)NN * HH;     // NN*HH
    float* agg    = z      + (size_t)NN * HH;     // NN*HH
    float* out    = (float*)d_out;

    // h = x @ W_in + b_in ; hidden = h * temp[0]
    k_in_linear<<<NN / 4, 64, 0, stream>>>(x, W_in, b_in, temp, h, hidden);

    for (int i = 0; i < 3; ++i) {
        // z = act(cur) @ layer_W[i] + layer_b[i]
        if (i == 0)
            k_hid_linear<false><<<NN / 4, 64, 0, stream>>>(h,   LW + i * HH * HH, Lb + i * HH, z);
        else
            k_hid_linear<true><<<NN / 4, 64, 0, stream>>>(agg, LW + i * HH * HH, Lb + i * HH, z);
        // agg = segment_sum(z[src] * ew, dst)
        hipMemsetAsync(agg, 0, (size_t)NN * HH * sizeof(float), stream);
        k_scatter<<<(NE * 64) / 256, 256, 0, stream>>>(src, dst, ew, z, agg);
        // hidden += relu(agg) * temp[i+1]
        k_accum<<<(NN * HH / 4) / 256, 256, 0, stream>>>(agg, hidden, temp, i + 1);
    }

    // out = hidden @ W_out + b_out
    k_hid_linear<false><<<NN / 4, 64, 0, stream>>>(hidden, W_out, b_out, out);
}

// Round 2
// 403.911 us; speedup vs baseline: 1.6261x; 1.6261x over previous
//
#include <hip/hip_runtime.h>

#define NN 50000
#define NE 800000
#define CIN 256
#define HH 64
#define NBLK 196   // ceil(NN/256)

// ---------------- in-linear: h = x @ W_in + b_in ; hidden = h * temp[0] -----
__global__ __launch_bounds__(64) void k_in_linear(
    const float* __restrict__ x, const float* __restrict__ W,
    const float* __restrict__ b, const float* __restrict__ temp,
    float* __restrict__ h, float* __restrict__ hidden)
{
    __shared__ float xs[4][CIN];
    const int n0 = blockIdx.x * 4;
    const int j = threadIdx.x;
    #pragma unroll
    for (int r = 0; r < 4; ++r) {
        ((float4*)&xs[r][0])[j] = ((const float4*)(x + (size_t)(n0 + r) * CIN))[j];
    }
    __syncthreads();
    const float bj = b[j];
    float a0 = bj, a1 = bj, a2 = bj, a3 = bj;
    #pragma unroll 8
    for (int k = 0; k < CIN; ++k) {
        const float w = W[k * HH + j];
        a0 = fmaf(xs[0][k], w, a0);
        a1 = fmaf(xs[1][k], w, a1);
        a2 = fmaf(xs[2][k], w, a2);
        a3 = fmaf(xs[3][k], w, a3);
    }
    const float t0 = temp[0];
    const size_t o = (size_t)n0 * HH + j;
    h[o]        = a0;  hidden[o]        = a0 * t0;
    h[o + HH]   = a1;  hidden[o + HH]   = a1 * t0;
    h[o + 2*HH] = a2;  hidden[o + 2*HH] = a2 * t0;
    h[o + 3*HH] = a3;  hidden[o + 3*HH] = a3 * t0;
}

// ---------------- CSR build ------------------------------------------------
// hist: per-edge count of dst + weighted degree (for the commuted bias term)
__global__ __launch_bounds__(256) void k_hist(
    const int* __restrict__ dst, const float* __restrict__ ew,
    int* __restrict__ cnt, float* __restrict__ degw)
{
    const int e = blockIdx.x * 256 + threadIdx.x;   // exact grid
    const int d = dst[e];
    atomicAdd(&cnt[d], 1);
    atomicAdd(&degw[d], ew[e]);
}

// scan1: per-block inclusive scan of cnt -> exclusive prescan in rowptr, block sums
__global__ __launch_bounds__(256) void k_scan1(
    const int* __restrict__ cnt, int* __restrict__ rowptr, int* __restrict__ bsum)
{
    __shared__ int s[256];
    const int t = threadIdx.x;
    const int i = blockIdx.x * 256 + t;
    const int v = (i < NN) ? cnt[i] : 0;
    s[t] = v; __syncthreads();
    #pragma unroll
    for (int off = 1; off < 256; off <<= 1) {
        const int add = (t >= off) ? s[t - off] : 0;
        __syncthreads();
        s[t] += add;
        __syncthreads();
    }
    if (i < NN) rowptr[i] = s[t] - v;      // exclusive within block
    if (t == 255) bsum[blockIdx.x] = s[t]; // block total
}

// scan2: exclusive scan of the block sums (single block)
__global__ __launch_bounds__(256) void k_scan2(int* __restrict__ bsum)
{
    __shared__ int s[256];
    const int t = threadIdx.x;
    const int v = (t < NBLK) ? bsum[t] : 0;
    s[t] = v; __syncthreads();
    #pragma unroll
    for (int off = 1; off < 256; off <<= 1) {
        const int add = (t >= off) ? s[t - off] : 0;
        __syncthreads();
        s[t] += add;
        __syncthreads();
    }
    if (t < NBLK) bsum[t] = s[t] - v;
}

// scan3: add block offsets; init cursor = rowptr
__global__ __launch_bounds__(256) void k_scan3(
    int* __restrict__ rowptr, const int* __restrict__ bsum, int* __restrict__ cursor)
{
    const int i = blockIdx.x * 256 + threadIdx.x;
    if (i < NN) {
        const int r = rowptr[i] + bsum[blockIdx.x];
        rowptr[i] = r;
        cursor[i] = r;
    }
}

// fill: counting-sort edges by dst; pack (src, weight) as int2
__global__ __launch_bounds__(256) void k_fill(
    const int* __restrict__ src, const int* __restrict__ dst,
    const float* __restrict__ ew, int* __restrict__ cursor,
    int2* __restrict__ epack)
{
    const int e = blockIdx.x * 256 + threadIdx.x;   // exact grid
    const int d = dst[e];
    const int pos = atomicAdd(&cursor[d], 1);
    epack[pos] = make_int2(src[e], __float_as_int(ew[e]));
}

// ---------------- fused layer ----------------------------------------------
// Per node n (one wave, lane j = channel):
//   t_j   = sum_{e into n} w_e * cur_in[src_e][j]      (pull gather, no atomics)
//   z_j   = sum_k t_k * W[k][j] + degw[n]*b[j]          (commuted linear+bias)
//   r     = relu(z); cur_out[n] = r; hidden[n] += r * temp[tidx]
__global__ __launch_bounds__(256) void k_layer(
    const float* __restrict__ cur_in, float* __restrict__ cur_out,
    float* __restrict__ hidden,
    const int2* __restrict__ epack, const int* __restrict__ rowptr,
    const int* __restrict__ cnt, const float* __restrict__ degw,
    const float* __restrict__ W, const float* __restrict__ bvec,
    const float* __restrict__ temp, int tidx)
{
    __shared__ float ts[4][HH];
    const int w = threadIdx.x >> 6;
    const int j = threadIdx.x & 63;
    const int n = blockIdx.x * 4 + w;
    const int rs = rowptr[n];
    const int re = rs + cnt[n];

    float acc = 0.0f;
    int k = rs;
    for (; k + 1 < re; k += 2) {
        const int2 p0 = epack[k];
        const int2 p1 = epack[k + 1];
        const float v0 = cur_in[(size_t)p0.x * HH + j];
        const float v1 = cur_in[(size_t)p1.x * HH + j];
        acc = fmaf(__int_as_float(p0.y), v0, acc);
        acc = fmaf(__int_as_float(p1.y), v1, acc);
    }
    if (k < re) {
        const int2 p = epack[k];
        acc = fmaf(__int_as_float(p.y), cur_in[(size_t)p.x * HH + j], acc);
    }
    // per-wave LDS row; no cross-wave sharing -> no barrier needed
    ts[w][j] = acc;
    float z = degw[n] * bvec[j];
    #pragma unroll 8
    for (int kk = 0; kk < HH; ++kk) {
        z = fmaf(ts[w][kk], W[kk * HH + j], z);
    }
    const float r = fmaxf(z, 0.0f);
    const size_t o = (size_t)n * HH + j;
    cur_out[o] = r;
    hidden[o] += r * temp[tidx];
}

// ---------------- plain 64x64 linear (final projection) --------------------
__global__ __launch_bounds__(64) void k_out_linear(
    const float* __restrict__ in, const float* __restrict__ W,
    const float* __restrict__ b, float* __restrict__ out)
{
    __shared__ float cs[4][HH];
    const int n0 = blockIdx.x * 4;
    const int j = threadIdx.x;
    #pragma unroll
    for (int r = 0; r < 4; ++r) cs[r][j] = in[(size_t)(n0 + r) * HH + j];
    __syncthreads();
    const float bj = b[j];
    float a0 = bj, a1 = bj, a2 = bj, a3 = bj;
    #pragma unroll 8
    for (int k = 0; k < HH; ++k) {
        const float w = W[k * HH + j];
        a0 = fmaf(cs[0][k], w, a0);
        a1 = fmaf(cs[1][k], w, a1);
        a2 = fmaf(cs[2][k], w, a2);
        a3 = fmaf(cs[3][k], w, a3);
    }
    const size_t o = (size_t)n0 * HH + j;
    out[o]        = a0;
    out[o + HH]   = a1;
    out[o + 2*HH] = a2;
    out[o + 3*HH] = a3;
}

extern "C" void kernel_launch(void* const* d_in, const int* in_sizes, int n_in,
                              void* d_out, int out_size, void* d_ws, size_t ws_size,
                              hipStream_t stream)
{
    const float* x     = (const float*)d_in[0];
    const int*   ei    = (const int*)d_in[1];
    const float* ew    = (const float*)d_in[2];
    const float* W_in  = (const float*)d_in[3];
    const float* b_in  = (const float*)d_in[4];
    const float* LW    = (const float*)d_in[5];
    const float* Lb    = (const float*)d_in[6];
    const float* W_out = (const float*)d_in[7];
    const float* b_out = (const float*)d_in[8];
    const float* temp  = (const float*)d_in[9];
    const int* src = ei;
    const int* dst = ei + NE;

    char* p = (char*)d_ws;
    float* h      = (float*)p;               p += (size_t)NN * HH * 4;
    float* hidden = (float*)p;               p += (size_t)NN * HH * 4;
    float* curA   = (float*)p;               p += (size_t)NN * HH * 4;
    float* curB   = (float*)p;               p += (size_t)NN * HH * 4;
    int*   cnt    = (int*)p;                 p += (size_t)NN * 4;
    float* degw   = (float*)p;               p += (size_t)NN * 4;   // adjacent to cnt: one memset
    int*   rowptr = (int*)p;                 p += (size_t)NN * 4;
    int*   cursor = (int*)p;                 p += (size_t)NN * 4;
    int*   bsum   = (int*)p;                 p += 256 * 4;
    int2*  epack  = (int2*)p;                p += (size_t)NE * 8;
    float* out    = (float*)d_out;

    // h = x @ W_in + b_in ; hidden = h * temp[0]
    k_in_linear<<<NN / 4, 64, 0, stream>>>(x, W_in, b_in, temp, h, hidden);

    // CSR build (once per call; reused by all 3 layers)
    hipMemsetAsync(cnt, 0, (size_t)2 * NN * 4, stream);     // cnt + degw
    k_hist <<<NE / 256, 256, 0, stream>>>(dst, ew, cnt, degw);
    k_scan1<<<NBLK, 256, 0, stream>>>(cnt, rowptr, bsum);
    k_scan2<<<1, 256, 0, stream>>>(bsum);
    k_scan3<<<NBLK, 256, 0, stream>>>(rowptr, bsum, cursor);
    k_fill <<<NE / 256, 256, 0, stream>>>(src, dst, ew, cursor, epack);

    // 3 fused propagation layers (gather-aggregate + linear + relu + accum)
    k_layer<<<NN / 4, 256, 0, stream>>>(h,    curA, hidden, epack, rowptr, cnt, degw,
                                        LW + 0 * HH * HH, Lb + 0 * HH, temp, 1);
    k_layer<<<NN / 4, 256, 0, stream>>>(curA, curB, hidden, epack, rowptr, cnt, degw,
                                        LW + 1 * HH * HH, Lb + 1 * HH, temp, 2);
    k_layer<<<NN / 4, 256, 0, stream>>>(curB, curA, hidden, epack, rowptr, cnt, degw,
                                        LW + 2 * HH * HH, Lb + 2 * HH, temp, 3);

    // out = hidden @ W_out + b_out
    k_out_linear<<<NN / 4, 64, 0, stream>>>(hidden, W_out, b_out, out);
}

// Round 3
// 305.274 us; speedup vs baseline: 2.1514x; 1.3231x over previous
//
#include <hip/hip_runtime.h>
#include <hip/hip_bf16.h>

#define NN 50000
#define NE 800000
#define CIN 256
#define HH 64
#define NBLK 196   // ceil(NN/256)

__device__ __forceinline__ float bf2f(ushort u) {
    union { unsigned int i; float f; } v; v.i = ((unsigned int)u) << 16; return v.f;
}
__device__ __forceinline__ ushort f2bf(float f) {
    __hip_bfloat16 b = __float2bfloat16(f);   // RNE
    return *reinterpret_cast<ushort*>(&b);
}

// ---------------- in-linear: h = x @ W_in + b_in ------------------------------
// Writes h as bf16 (gather source for layer 1) and hidden = h*temp[0] (fp32).
__global__ __launch_bounds__(64) void k_in_linear(
    const float* __restrict__ x, const float* __restrict__ W,
    const float* __restrict__ b, const float* __restrict__ temp,
    ushort* __restrict__ h_bf, float* __restrict__ hidden)
{
    __shared__ float xs[4][CIN];
    const int n0 = blockIdx.x * 4;
    const int j = threadIdx.x;
    #pragma unroll
    for (int r = 0; r < 4; ++r)
        ((float4*)&xs[r][0])[j] = ((const float4*)(x + (size_t)(n0 + r) * CIN))[j];
    __syncthreads();
    const float bj = b[j];
    float a0 = bj, a1 = bj, a2 = bj, a3 = bj;
    #pragma unroll 8
    for (int q = 0; q < CIN / 4; ++q) {
        const float4 t0 = ((const float4*)xs[0])[q];
        const float4 t1 = ((const float4*)xs[1])[q];
        const float4 t2 = ((const float4*)xs[2])[q];
        const float4 t3 = ((const float4*)xs[3])[q];
        const float w0 = W[(4*q+0)*HH + j];
        const float w1 = W[(4*q+1)*HH + j];
        const float w2 = W[(4*q+2)*HH + j];
        const float w3 = W[(4*q+3)*HH + j];
        a0 = fmaf(t0.x,w0,a0); a0 = fmaf(t0.y,w1,a0); a0 = fmaf(t0.z,w2,a0); a0 = fmaf(t0.w,w3,a0);
        a1 = fmaf(t1.x,w0,a1); a1 = fmaf(t1.y,w1,a1); a1 = fmaf(t1.z,w2,a1); a1 = fmaf(t1.w,w3,a1);
        a2 = fmaf(t2.x,w0,a2); a2 = fmaf(t2.y,w1,a2); a2 = fmaf(t2.z,w2,a2); a2 = fmaf(t2.w,w3,a2);
        a3 = fmaf(t3.x,w0,a3); a3 = fmaf(t3.y,w1,a3); a3 = fmaf(t3.z,w2,a3); a3 = fmaf(t3.w,w3,a3);
    }
    const float t0v = temp[0];
    const size_t o = (size_t)n0 * HH + j;
    h_bf[o]        = f2bf(a0);  hidden[o]        = a0 * t0v;
    h_bf[o + HH]   = f2bf(a1);  hidden[o + HH]   = a1 * t0v;
    h_bf[o + 2*HH] = f2bf(a2);  hidden[o + 2*HH] = a2 * t0v;
    h_bf[o + 3*HH] = f2bf(a3);  hidden[o + 3*HH] = a3 * t0v;
}

// ---------------- CSR build ---------------------------------------------------
__global__ __launch_bounds__(256) void k_hist(
    const int* __restrict__ dst, const float* __restrict__ ew,
    int* __restrict__ cnt, float* __restrict__ degw)
{
    const int e = blockIdx.x * 256 + threadIdx.x;   // exact grid
    const int d = dst[e];
    atomicAdd(&cnt[d], 1);
    atomicAdd(&degw[d], ew[e]);
}

__global__ __launch_bounds__(256) void k_scan1(
    const int* __restrict__ cnt, int* __restrict__ rowptr, int* __restrict__ bsum)
{
    __shared__ int s[256];
    const int t = threadIdx.x;
    const int i = blockIdx.x * 256 + t;
    const int v = (i < NN) ? cnt[i] : 0;
    s[t] = v; __syncthreads();
    #pragma unroll
    for (int off = 1; off < 256; off <<= 1) {
        const int add = (t >= off) ? s[t - off] : 0;
        __syncthreads();
        s[t] += add;
        __syncthreads();
    }
    if (i < NN) rowptr[i] = s[t] - v;
    if (t == 255) bsum[blockIdx.x] = s[t];
}

__global__ __launch_bounds__(256) void k_scan2(int* __restrict__ bsum)
{
    __shared__ int s[256];
    const int t = threadIdx.x;
    const int v = (t < NBLK) ? bsum[t] : 0;
    s[t] = v; __syncthreads();
    #pragma unroll
    for (int off = 1; off < 256; off <<= 1) {
        const int add = (t >= off) ? s[t - off] : 0;
        __syncthreads();
        s[t] += add;
        __syncthreads();
    }
    if (t < NBLK) bsum[t] = s[t] - v;
}

__global__ __launch_bounds__(256) void k_scan3(
    int* __restrict__ rowptr, const int* __restrict__ bsum, int* __restrict__ cursor)
{
    const int i = blockIdx.x * 256 + threadIdx.x;
    if (i < NN) {
        const int r = rowptr[i] + bsum[blockIdx.x];
        rowptr[i] = r;
        cursor[i] = r;
    }
}

__global__ __launch_bounds__(256) void k_fill(
    const int* __restrict__ src, const int* __restrict__ dst,
    const float* __restrict__ ew, int* __restrict__ cursor,
    int2* __restrict__ epack)
{
    const int e = blockIdx.x * 256 + threadIdx.x;   // exact grid
    const int d = dst[e];
    const int pos = atomicAdd(&cursor[d], 1);
    epack[pos] = make_int2(src[e], __float_as_int(ew[e]));
}

// ---------------- fused layer -------------------------------------------------
// Per node n (one wave, lane j = channel):
//   t_j = sum_e w_e * cur_in[src_e][j]   (bf16 gather, fp32 accumulate)
//   z_j = sum_k t_k * W[k][j] + degw[n]*b[j]
//   r = relu(z); cur_out[n]=bf16(r); hidden[n] += r*temp[tidx]
__global__ __launch_bounds__(256) void k_layer(
    const ushort* __restrict__ cur_in, ushort* __restrict__ cur_out,
    float* __restrict__ hidden,
    const int2* __restrict__ epack, const int* __restrict__ rowptr,
    const int* __restrict__ cnt, const float* __restrict__ degw,
    const float* __restrict__ W, const float* __restrict__ bvec,
    const float* __restrict__ temp, int tidx)
{
    __shared__ float ts[4][HH];
    const int w = threadIdx.x >> 6;
    const int j = threadIdx.x & 63;
    const int n = blockIdx.x * 4 + w;
    const int rs = __builtin_amdgcn_readfirstlane(rowptr[n]);
    const int rc = __builtin_amdgcn_readfirstlane(cnt[n]);
    const int re = rs + rc;

    float acc = 0.0f;
    int k = rs;
    for (; k + 4 <= re; k += 4) {
        const int2 p0 = epack[k + 0];
        const int2 p1 = epack[k + 1];
        const int2 p2 = epack[k + 2];
        const int2 p3 = epack[k + 3];
        const float v0 = bf2f(cur_in[(size_t)p0.x * HH + j]);
        const float v1 = bf2f(cur_in[(size_t)p1.x * HH + j]);
        const float v2 = bf2f(cur_in[(size_t)p2.x * HH + j]);
        const float v3 = bf2f(cur_in[(size_t)p3.x * HH + j]);
        acc = fmaf(__int_as_float(p0.y), v0, acc);
        acc = fmaf(__int_as_float(p1.y), v1, acc);
        acc = fmaf(__int_as_float(p2.y), v2, acc);
        acc = fmaf(__int_as_float(p3.y), v3, acc);
    }
    for (; k < re; ++k) {
        const int2 p = epack[k];
        acc = fmaf(__int_as_float(p.y), bf2f(cur_in[(size_t)p.x * HH + j]), acc);
    }

    ts[w][j] = acc;                       // wave-private row: no barrier needed
    float z = degw[n] * bvec[j];
    #pragma unroll
    for (int q = 0; q < HH / 4; ++q) {
        const float4 t4 = ((const float4*)ts[w])[q];
        z = fmaf(t4.x, W[(4*q+0)*HH + j], z);
        z = fmaf(t4.y, W[(4*q+1)*HH + j], z);
        z = fmaf(t4.z, W[(4*q+2)*HH + j], z);
        z = fmaf(t4.w, W[(4*q+3)*HH + j], z);
    }
    const float r = fmaxf(z, 0.0f);
    const size_t o = (size_t)n * HH + j;
    cur_out[o] = f2bf(r);
    hidden[o] += r * temp[tidx];
}

// ---------------- final projection: out = hidden @ W_out + b_out --------------
__global__ __launch_bounds__(64) void k_out_linear(
    const float* __restrict__ in, const float* __restrict__ W,
    const float* __restrict__ b, float* __restrict__ out)
{
    __shared__ float cs[4][HH];
    const int n0 = blockIdx.x * 4;
    const int j = threadIdx.x;
    #pragma unroll
    for (int r = 0; r < 4; ++r) cs[r][j] = in[(size_t)(n0 + r) * HH + j];
    __syncthreads();
    const float bj = b[j];
    float a0 = bj, a1 = bj, a2 = bj, a3 = bj;
    #pragma unroll
    for (int q = 0; q < HH / 4; ++q) {
        const float4 t0 = ((const float4*)cs[0])[q];
        const float4 t1 = ((const float4*)cs[1])[q];
        const float4 t2 = ((const float4*)cs[2])[q];
        const float4 t3 = ((const float4*)cs[3])[q];
        const float w0 = W[(4*q+0)*HH + j];
        const float w1 = W[(4*q+1)*HH + j];
        const float w2 = W[(4*q+2)*HH + j];
        const float w3 = W[(4*q+3)*HH + j];
        a0 = fmaf(t0.x,w0,a0); a0 = fmaf(t0.y,w1,a0); a0 = fmaf(t0.z,w2,a0); a0 = fmaf(t0.w,w3,a0);
        a1 = fmaf(t1.x,w0,a1); a1 = fmaf(t1.y,w1,a1); a1 = fmaf(t1.z,w2,a1); a1 = fmaf(t1.w,w3,a1);
        a2 = fmaf(t2.x,w0,a2); a2 = fmaf(t2.y,w1,a2); a2 = fmaf(t2.z,w2,a2); a2 = fmaf(t2.w,w3,a2);
        a3 = fmaf(t3.x,w0,a3); a3 = fmaf(t3.y,w1,a3); a3 = fmaf(t3.z,w2,a3); a3 = fmaf(t3.w,w3,a3);
    }
    const size_t o = (size_t)n0 * HH + j;
    out[o]        = a0;
    out[o + HH]   = a1;
    out[o + 2*HH] = a2;
    out[o + 3*HH] = a3;
}

extern "C" void kernel_launch(void* const* d_in, const int* in_sizes, int n_in,
                              void* d_out, int out_size, void* d_ws, size_t ws_size,
                              hipStream_t stream)
{
    const float* x     = (const float*)d_in[0];
    const int*   ei    = (const int*)d_in[1];
    const float* ew    = (const float*)d_in[2];
    const float* W_in  = (const float*)d_in[3];
    const float* b_in  = (const float*)d_in[4];
    const float* LW    = (const float*)d_in[5];
    const float* Lb    = (const float*)d_in[6];
    const float* W_out = (const float*)d_in[7];
    const float* b_out = (const float*)d_in[8];
    const float* temp  = (const float*)d_in[9];
    const int* src = ei;
    const int* dst = ei + NE;

    char* p = (char*)d_ws;
    float*  hidden = (float*)p;   p += (size_t)NN * HH * 4;
    ushort* h_bf   = (ushort*)p;  p += (size_t)NN * HH * 2;
    ushort* curA   = (ushort*)p;  p += (size_t)NN * HH * 2;
    ushort* curB   = (ushort*)p;  p += (size_t)NN * HH * 2;
    int*    cnt    = (int*)p;     p += (size_t)NN * 4;
    float*  degw   = (float*)p;   p += (size_t)NN * 4;   // adjacent to cnt: one memset
    int*    rowptr = (int*)p;     p += (size_t)NN * 4;
    int*    cursor = (int*)p;     p += (size_t)NN * 4;
    int*    bsum   = (int*)p;     p += 256 * 4;
    int2*   epack  = (int2*)p;    p += (size_t)NE * 8;
    float*  out    = (float*)d_out;

    // h (bf16) + hidden init
    k_in_linear<<<NN / 4, 64, 0, stream>>>(x, W_in, b_in, temp, h_bf, hidden);

    // CSR build (once; reused by all 3 layers)
    hipMemsetAsync(cnt, 0, (size_t)2 * NN * 4, stream);
    k_hist <<<NE / 256, 256, 0, stream>>>(dst, ew, cnt, degw);
    k_scan1<<<NBLK, 256, 0, stream>>>(cnt, rowptr, bsum);
    k_scan2<<<1, 256, 0, stream>>>(bsum);
    k_scan3<<<NBLK, 256, 0, stream>>>(rowptr, bsum, cursor);
    k_fill <<<NE / 256, 256, 0, stream>>>(src, dst, ew, cursor, epack);

    // 3 fused propagation layers
    k_layer<<<NN / 4, 256, 0, stream>>>(h_bf, curA, hidden, epack, rowptr, cnt, degw,
                                        LW + 0 * HH * HH, Lb + 0 * HH, temp, 1);
    k_layer<<<NN / 4, 256, 0, stream>>>(curA, curB, hidden, epack, rowptr, cnt, degw,
                                        LW + 1 * HH * HH, Lb + 1 * HH, temp, 2);
    k_layer<<<NN / 4, 256, 0, stream>>>(curB, curA, hidden, epack, rowptr, cnt, degw,
                                        LW + 2 * HH * HH, Lb + 2 * HH, temp, 3);

    // out = hidden @ W_out + b_out
    k_out_linear<<<NN / 4, 64, 0, stream>>>(hidden, W_out, b_out, out);
}

// Round 4
// 244.305 us; speedup vs baseline: 2.6884x; 1.2496x over previous
//
#include <hip/hip_runtime.h>
#include <hip/hip_bf16.h>

#define NN 50000
#define NE 800000
#define CIN 256
#define HH 64
#define NBLK 196          // ceil(NN/256) for scans
#define NHB (NE / 256)    // 3125 histogram blocks
#define NLB (NN / 16)     // 3125 in-linear blocks (16 nodes each)
#define WSCALE 67108864.0f   // 2^26 fixed-point scale for edge weights
#define WMASK ((1ull << 42) - 1)

typedef unsigned long long u64;

__device__ __forceinline__ float bf2f(ushort u) {
    union { unsigned int i; float f; } v; v.i = ((unsigned int)u) << 16; return v.f;
}
__device__ __forceinline__ ushort f2bf(float f) {
    __hip_bfloat16 b = __float2bfloat16(f);   // RNE
    return *reinterpret_cast<ushort*>(&b);
}

// ---------------- fused: edge histogram (blocks < NHB) | in-linear (rest) ----
// Hist: one packed u64 atomic per edge -> count (bits 42+), fixed-point
// weighted degree (bits 0..41). Atomic return value = rank of edge within its
// dst bucket (makes k_fill atomic-free).
// In-linear: per wave, 4 nodes; h = x @ W_in + b_in -> bf16; hidden = h*temp0.
__global__ __launch_bounds__(256) void k_inlin_hist(
    const float* __restrict__ x, const float* __restrict__ W,
    const float* __restrict__ b, const float* __restrict__ temp,
    const int* __restrict__ dst, const float* __restrict__ ew,
    u64* __restrict__ packed, ushort* __restrict__ rank,
    ushort* __restrict__ h_bf, float* __restrict__ hidden)
{
    __shared__ float xs[16][CIN];
    if (blockIdx.x < NHB) {
        const int e = blockIdx.x * 256 + threadIdx.x;   // exact
        const int d = dst[e];
        const u64 inc = (1ull << 42) | (u64)(ew[e] * WSCALE + 0.5f);
        const u64 old = atomicAdd(&packed[d], inc);
        rank[e] = (ushort)(old >> 42);
        return;
    }
    const int w = threadIdx.x >> 6;
    const int j = threadIdx.x & 63;
    const int n0 = (blockIdx.x - NHB) * 16 + w * 4;
    #pragma unroll
    for (int r = 0; r < 4; ++r)
        ((float4*)&xs[w*4 + r][0])[j] = ((const float4*)(x + (size_t)(n0 + r) * CIN))[j];
    // wave-private LDS rows: no block barrier needed
    const float bj = b[j];
    float a0 = bj, a1 = bj, a2 = bj, a3 = bj;
    #pragma unroll 8
    for (int q = 0; q < CIN / 4; ++q) {
        const float4 t0 = ((const float4*)xs[w*4+0])[q];
        const float4 t1 = ((const float4*)xs[w*4+1])[q];
        const float4 t2 = ((const float4*)xs[w*4+2])[q];
        const float4 t3 = ((const float4*)xs[w*4+3])[q];
        const float w0 = W[(4*q+0)*HH + j];
        const float w1 = W[(4*q+1)*HH + j];
        const float w2 = W[(4*q+2)*HH + j];
        const float w3 = W[(4*q+3)*HH + j];
        a0 = fmaf(t0.x,w0,a0); a0 = fmaf(t0.y,w1,a0); a0 = fmaf(t0.z,w2,a0); a0 = fmaf(t0.w,w3,a0);
        a1 = fmaf(t1.x,w0,a1); a1 = fmaf(t1.y,w1,a1); a1 = fmaf(t1.z,w2,a1); a1 = fmaf(t1.w,w3,a1);
        a2 = fmaf(t2.x,w0,a2); a2 = fmaf(t2.y,w1,a2); a2 = fmaf(t2.z,w2,a2); a2 = fmaf(t2.w,w3,a2);
        a3 = fmaf(t3.x,w0,a3); a3 = fmaf(t3.y,w1,a3); a3 = fmaf(t3.z,w2,a3); a3 = fmaf(t3.w,w3,a3);
    }
    const float t0v = temp[0];
    const size_t o = (size_t)n0 * HH + j;
    h_bf[o]        = f2bf(a0);  hidden[o]        = a0 * t0v;
    h_bf[o + HH]   = f2bf(a1);  hidden[o + HH]   = a1 * t0v;
    h_bf[o + 2*HH] = f2bf(a2);  hidden[o + 2*HH] = a2 * t0v;
    h_bf[o + 3*HH] = f2bf(a3);  hidden[o + 3*HH] = a3 * t0v;
}

// ---------------- scans: unpack + exclusive prefix over counts ---------------
__global__ __launch_bounds__(256) void k_scan1(
    const u64* __restrict__ packed, int* __restrict__ cnt, float* __restrict__ degw,
    int* __restrict__ rowptr, int* __restrict__ bsum)
{
    __shared__ int s[256];
    const int t = threadIdx.x;
    const int i = blockIdx.x * 256 + t;
    int v = 0;
    if (i < NN) {
        const u64 pk = packed[i];
        v = (int)(pk >> 42);
        cnt[i] = v;
        degw[i] = (float)(pk & WMASK) * (1.0f / WSCALE);
    }
    s[t] = v; __syncthreads();
    #pragma unroll
    for (int off = 1; off < 256; off <<= 1) {
        const int add = (t >= off) ? s[t - off] : 0;
        __syncthreads();
        s[t] += add;
        __syncthreads();
    }
    if (i < NN) rowptr[i] = s[t] - v;
    if (t == 255) bsum[blockIdx.x] = s[t];
}

__global__ __launch_bounds__(256) void k_scan2(int* __restrict__ bsum)
{
    __shared__ int s[256];
    const int t = threadIdx.x;
    const int v = (t < NBLK) ? bsum[t] : 0;
    s[t] = v; __syncthreads();
    #pragma unroll
    for (int off = 1; off < 256; off <<= 1) {
        const int add = (t >= off) ? s[t - off] : 0;
        __syncthreads();
        s[t] += add;
        __syncthreads();
    }
    if (t < NBLK) bsum[t] = s[t] - v;
}

__global__ __launch_bounds__(256) void k_scan3(
    int* __restrict__ rowptr, const int* __restrict__ bsum)
{
    const int i = blockIdx.x * 256 + threadIdx.x;
    if (i < NN) rowptr[i] += bsum[blockIdx.x];
}

// ---------------- fill: counting-sort placement, NO atomics ------------------
__global__ __launch_bounds__(256) void k_fill(
    const int* __restrict__ src, const int* __restrict__ dst,
    const float* __restrict__ ew, const ushort* __restrict__ rank,
    const int* __restrict__ rowptr, int2* __restrict__ epack)
{
    const int e = blockIdx.x * 256 + threadIdx.x;   // exact
    const int d = dst[e];
    const int pos = rowptr[d] + (int)rank[e];
    epack[pos] = make_int2(src[e], __float_as_int(ew[e]));
}

// ---------------- fused layer -------------------------------------------------
// Per node n (one wave, lane j = channel):
//   t_j = sum_e w_e * cur_in[src_e][j]   (bf16 gather, fp32 accumulate)
//   z_j = sum_k t_k * W[k][j] + degw[n]*b[j] ; r = relu(z)
// FINAL=false: cur_out = bf16(r); hidden += r*temp
// FINAL=true : hid = hidden + r*temp (in-register) ; out = hid @ W_out + b_out
template<bool FINAL>
__global__ __launch_bounds__(256) void k_layer(
    const ushort* __restrict__ cur_in, ushort* __restrict__ cur_out,
    float* __restrict__ hidden,
    const int2* __restrict__ epack, const int* __restrict__ rowptr,
    const int* __restrict__ cnt, const float* __restrict__ degw,
    const float* __restrict__ W, const float* __restrict__ bvec,
    const float* __restrict__ temp, int tidx,
    const float* __restrict__ Wout, const float* __restrict__ bout,
    float* __restrict__ outp)
{
    __shared__ float ts[4][HH];
    const int w = threadIdx.x >> 6;
    const int j = threadIdx.x & 63;
    const int n = blockIdx.x * 4 + w;
    const int rs = __builtin_amdgcn_readfirstlane(rowptr[n]);
    const int rc = __builtin_amdgcn_readfirstlane(cnt[n]);
    const int re = rs + rc;

    float acc = 0.0f;
    int k = rs;
    for (; k + 4 <= re; k += 4) {
        const int2 p0 = epack[k + 0];
        const int2 p1 = epack[k + 1];
        const int2 p2 = epack[k + 2];
        const int2 p3 = epack[k + 3];
        const float v0 = bf2f(cur_in[(size_t)p0.x * HH + j]);
        const float v1 = bf2f(cur_in[(size_t)p1.x * HH + j]);
        const float v2 = bf2f(cur_in[(size_t)p2.x * HH + j]);
        const float v3 = bf2f(cur_in[(size_t)p3.x * HH + j]);
        acc = fmaf(__int_as_float(p0.y), v0, acc);
        acc = fmaf(__int_as_float(p1.y), v1, acc);
        acc = fmaf(__int_as_float(p2.y), v2, acc);
        acc = fmaf(__int_as_float(p3.y), v3, acc);
    }
    for (; k < re; ++k) {
        const int2 p = epack[k];
        acc = fmaf(__int_as_float(p.y), bf2f(cur_in[(size_t)p.x * HH + j]), acc);
    }

    ts[w][j] = acc;                       // wave-private row: no barrier needed
    float z = degw[n] * bvec[j];
    #pragma unroll
    for (int q = 0; q < HH / 4; ++q) {
        const float4 t4 = ((const float4*)ts[w])[q];
        z = fmaf(t4.x, W[(4*q+0)*HH + j], z);
        z = fmaf(t4.y, W[(4*q+1)*HH + j], z);
        z = fmaf(t4.z, W[(4*q+2)*HH + j], z);
        z = fmaf(t4.w, W[(4*q+3)*HH + j], z);
    }
    const float r = fmaxf(z, 0.0f);
    const size_t o = (size_t)n * HH + j;
    if (!FINAL) {
        cur_out[o] = f2bf(r);
        hidden[o] += r * temp[tidx];
    } else {
        const float hid = hidden[o] + r * temp[tidx];
        ts[w][j] = hid;                   // reuse wave row for final projection
        float z2 = bout[j];
        #pragma unroll
        for (int q = 0; q < HH / 4; ++q) {
            const float4 t4 = ((const float4*)ts[w])[q];
            z2 = fmaf(t4.x, Wout[(4*q+0)*HH + j], z2);
            z2 = fmaf(t4.y, Wout[(4*q+1)*HH + j], z2);
            z2 = fmaf(t4.z, Wout[(4*q+2)*HH + j], z2);
            z2 = fmaf(t4.w, Wout[(4*q+3)*HH + j], z2);
        }
        outp[o] = z2;
    }
}

extern "C" void kernel_launch(void* const* d_in, const int* in_sizes, int n_in,
                              void* d_out, int out_size, void* d_ws, size_t ws_size,
                              hipStream_t stream)
{
    const float* x     = (const float*)d_in[0];
    const int*   ei    = (const int*)d_in[1];
    const float* ew    = (const float*)d_in[2];
    const float* W_in  = (const float*)d_in[3];
    const float* b_in  = (const float*)d_in[4];
    const float* LW    = (const float*)d_in[5];
    const float* Lb    = (const float*)d_in[6];
    const float* W_out = (const float*)d_in[7];
    const float* b_out = (const float*)d_in[8];
    const float* temp  = (const float*)d_in[9];
    const int* src = ei;
    const int* dst = ei + NE;

    char* p = (char*)d_ws;
    float*  hidden = (float*)p;   p += (size_t)NN * HH * 4;   // 12.8 MB
    ushort* h_bf   = (ushort*)p;  p += (size_t)NN * HH * 2;   // 6.4 MB
    ushort* curA   = (ushort*)p;  p += (size_t)NN * HH * 2;
    ushort* curB   = (ushort*)p;  p += (size_t)NN * HH * 2;
    int2*   epack  = (int2*)p;    p += (size_t)NE * 8;        // 6.4 MB
    u64*    packed = (u64*)p;     p += (size_t)NN * 8;        // 0.4 MB
    ushort* rank   = (ushort*)p;  p += (size_t)NE * 2;        // 1.6 MB
    int*    cnt    = (int*)p;     p += (size_t)NN * 4;
    float*  degw   = (float*)p;   p += (size_t)NN * 4;
    int*    rowptr = (int*)p;     p += (size_t)NN * 4;
    int*    bsum   = (int*)p;     p += 256 * 4;
    float*  out    = (float*)d_out;

    // packed histogram must start at zero
    hipMemsetAsync(packed, 0, (size_t)NN * 8, stream);

    // hist (RMW-latency-bound) fused with in-linear (VALU-bound): they overlap
    k_inlin_hist<<<NHB + NLB, 256, 0, stream>>>(x, W_in, b_in, temp, dst, ew,
                                                packed, rank, h_bf, hidden);
    // prefix-scan counts -> rowptr; unpack degw
    k_scan1<<<NBLK, 256, 0, stream>>>(packed, cnt, degw, rowptr, bsum);
    k_scan2<<<1, 256, 0, stream>>>(bsum);
    k_scan3<<<NBLK, 256, 0, stream>>>(rowptr, bsum);
    // atomic-free counting-sort placement
    k_fill<<<NHB, 256, 0, stream>>>(src, dst, ew, rank, rowptr, epack);

    // 3 fused propagation layers; layer 3 also does the final projection
    k_layer<false><<<NN / 4, 256, 0, stream>>>(h_bf, curA, hidden, epack, rowptr, cnt, degw,
                                               LW + 0 * HH * HH, Lb + 0 * HH, temp, 1,
                                               nullptr, nullptr, nullptr);
    k_layer<false><<<NN / 4, 256, 0, stream>>>(curA, curB, hidden, epack, rowptr, cnt, degw,
                                               LW + 1 * HH * HH, Lb + 1 * HH, temp, 2,
                                               nullptr, nullptr, nullptr);
    k_layer<true><<<NN / 4, 256, 0, stream>>>(curB, nullptr, hidden, epack, rowptr, cnt, degw,
                                              LW + 2 * HH * HH, Lb + 2 * HH, temp, 3,
                                              W_out, b_out, out);
}

// Round 5
// 219.718 us; speedup vs baseline: 2.9892x; 1.1119x over previous
//
#include <hip/hip_runtime.h>
#include <hip/hip_bf16.h>

#define NN 50000
#define NE 800000
#define CIN 256
#define HH 64
#define NBLK 196          // ceil(NN/256) for scans
#define NHB (NE / 256)    // 3125 histogram blocks
#define NGB 782           // ceil(NN/64) GEMM blocks (64 rows each)
#define WSCALE 67108864.0f   // 2^26 fixed-point scale for edge weights
#define WMASK ((1ull << 42) - 1)

typedef unsigned long long u64;
typedef __attribute__((ext_vector_type(8))) short short8;
typedef __attribute__((ext_vector_type(4))) float f32x4;

__device__ __forceinline__ float bf2f(ushort u) {
    union { unsigned int i; float f; } v; v.i = ((unsigned int)u) << 16; return v.f;
}
__device__ __forceinline__ ushort f2bf(float f) {
    __hip_bfloat16 b = __float2bfloat16(f);   // RNE
    return *reinterpret_cast<ushort*>(&b);
}

// ---------------- prep: W_in -> bf16, pre-swizzled into MFMA B-frag layout ---
// Wp[((t*8+s)*64 + l)*8 + i] = bf16( W[k = s*32+(l>>4)*8+i][col = t*16+(l&15)] )
__global__ __launch_bounds__(256) void k_prepW(
    const float* __restrict__ W, ushort* __restrict__ Wp)
{
    const int tid = blockIdx.x * 256 + threadIdx.x;   // 16384 total
    const int i = tid & 7;
    const int l = (tid >> 3) & 63;
    const int s = (tid >> 9) & 7;
    const int t = tid >> 12;
    const int k = s * 32 + (l >> 4) * 8 + i;
    const int c = t * 16 + (l & 15);
    Wp[tid] = f2bf(W[k * HH + c]);
}

// ---------------- fused: edge histogram (blocks < NHB) | MFMA in-linear ------
// Hist: one packed u64 atomic per edge -> count (bits 42+), fixed-point
// weighted degree (bits 0..41); atomic return = rank of edge in its dst bucket.
// GEMM: h = x @ W_in + b_in (bf16 MFMA, fp32 acc) -> h_bf (bf16), hidden=h*t0.
__global__ __launch_bounds__(256) void k_inlin_hist(
    const float* __restrict__ x, const ushort* __restrict__ Wp,
    const float* __restrict__ b, const float* __restrict__ temp,
    const int* __restrict__ dst, const float* __restrict__ ew,
    u64* __restrict__ packed, ushort* __restrict__ rank,
    ushort* __restrict__ h_bf, float* __restrict__ hidden)
{
    if (blockIdx.x < NHB) {
        const int e = blockIdx.x * 256 + threadIdx.x;   // exact
        const int d = dst[e];
        const u64 inc = (1ull << 42) | (u64)(ew[e] * WSCALE + 0.5f);
        const u64 old = atomicAdd(&packed[d], inc);
        rank[e] = (ushort)(old >> 42);
        return;
    }
    const int w = threadIdx.x >> 6;          // wave 0..3
    const int l = threadIdx.x & 63;
    const int R0 = (blockIdx.x - NHB) * 64 + w * 16;
    const int arow = R0 + (l & 15);
    const int xrow = (arow < NN) ? arow : (NN - 1);
    const int kg = l >> 4;
    const float* xr = x + (size_t)xrow * CIN + kg * 8;
    const short8* WpV = (const short8*)Wp;

    f32x4 acc0 = {0,0,0,0}, acc1 = {0,0,0,0}, acc2 = {0,0,0,0}, acc3 = {0,0,0,0};
    #pragma unroll
    for (int s = 0; s < 8; ++s) {
        const float4 xa = *(const float4*)(xr + s * 32);
        const float4 xb = *(const float4*)(xr + s * 32 + 4);
        short8 af;
        af[0] = (short)f2bf(xa.x); af[1] = (short)f2bf(xa.y);
        af[2] = (short)f2bf(xa.z); af[3] = (short)f2bf(xa.w);
        af[4] = (short)f2bf(xb.x); af[5] = (short)f2bf(xb.y);
        af[6] = (short)f2bf(xb.z); af[7] = (short)f2bf(xb.w);
        acc0 = __builtin_amdgcn_mfma_f32_16x16x32_bf16(af, WpV[(0*8+s)*64 + l], acc0, 0, 0, 0);
        acc1 = __builtin_amdgcn_mfma_f32_16x16x32_bf16(af, WpV[(1*8+s)*64 + l], acc1, 0, 0, 0);
        acc2 = __builtin_amdgcn_mfma_f32_16x16x32_bf16(af, WpV[(2*8+s)*64 + l], acc2, 0, 0, 0);
        acc3 = __builtin_amdgcn_mfma_f32_16x16x32_bf16(af, WpV[(3*8+s)*64 + l], acc3, 0, 0, 0);
    }
    const float t0v = temp[0];
    const int colb = l & 15;
    const int rbase = R0 + (l >> 4) * 4;
    #pragma unroll
    for (int t = 0; t < 4; ++t) {
        const f32x4 a = (t == 0) ? acc0 : (t == 1) ? acc1 : (t == 2) ? acc2 : acc3;
        const float bb = b[t * 16 + colb];
        #pragma unroll
        for (int r = 0; r < 4; ++r) {
            const int row = rbase + r;
            if (row < NN) {
                const float v = a[r] + bb;
                const size_t o = (size_t)row * HH + t * 16 + colb;
                h_bf[o]   = f2bf(v);
                hidden[o] = v * t0v;
            }
        }
    }
}

// ---------------- scans: unpack + exclusive prefix over counts ---------------
__global__ __launch_bounds__(256) void k_scan1(
    const u64* __restrict__ packed, int* __restrict__ cnt, float* __restrict__ degw,
    int* __restrict__ rowptr, int* __restrict__ bsum)
{
    __shared__ int s[256];
    const int t = threadIdx.x;
    const int i = blockIdx.x * 256 + t;
    int v = 0;
    if (i < NN) {
        const u64 pk = packed[i];
        v = (int)(pk >> 42);
        cnt[i] = v;
        degw[i] = (float)(pk & WMASK) * (1.0f / WSCALE);
    }
    s[t] = v; __syncthreads();
    #pragma unroll
    for (int off = 1; off < 256; off <<= 1) {
        const int add = (t >= off) ? s[t - off] : 0;
        __syncthreads();
        s[t] += add;
        __syncthreads();
    }
    if (i < NN) rowptr[i] = s[t] - v;
    if (t == 255) bsum[blockIdx.x] = s[t];
}

__global__ __launch_bounds__(256) void k_scan2(int* __restrict__ bsum)
{
    __shared__ int s[256];
    const int t = threadIdx.x;
    const int v = (t < NBLK) ? bsum[t] : 0;
    s[t] = v; __syncthreads();
    #pragma unroll
    for (int off = 1; off < 256; off <<= 1) {
        const int add = (t >= off) ? s[t - off] : 0;
        __syncthreads();
        s[t] += add;
        __syncthreads();
    }
    if (t < NBLK) bsum[t] = s[t] - v;
}

__global__ __launch_bounds__(256) void k_scan3(
    int* __restrict__ rowptr, const int* __restrict__ bsum)
{
    const int i = blockIdx.x * 256 + threadIdx.x;
    if (i < NN) rowptr[i] += bsum[blockIdx.x];
}

// ---------------- fill: counting-sort placement, NO atomics ------------------
__global__ __launch_bounds__(256) void k_fill(
    const int* __restrict__ src, const int* __restrict__ dst,
    const float* __restrict__ ew, const ushort* __restrict__ rank,
    const int* __restrict__ rowptr, int2* __restrict__ epack)
{
    const int e = blockIdx.x * 256 + threadIdx.x;   // exact
    if (blockIdx.x == 0 && threadIdx.x < 8)
        epack[NE + threadIdx.x] = make_int2(0, 0);  // pad for masked 8-chunks
    const int d = dst[e];
    const int pos = rowptr[d] + (int)rank[e];
    epack[pos] = make_int2(src[e], __float_as_int(ew[e]));
}

// ---------------- fused layer -------------------------------------------------
// Per node n (one wave, lane j = channel): masked 8-wide gather chunks
// (always 8 loads in flight, no dependent tail), then 64x64 matvec via LDS row.
template<bool FINAL>
__global__ __launch_bounds__(256) void k_layer(
    const ushort* __restrict__ cur_in, ushort* __restrict__ cur_out,
    float* __restrict__ hidden,
    const int2* __restrict__ epack, const int* __restrict__ rowptr,
    const int* __restrict__ cnt, const float* __restrict__ degw,
    const float* __restrict__ W, const float* __restrict__ bvec,
    const float* __restrict__ temp, int tidx,
    const float* __restrict__ Wout, const float* __restrict__ bout,
    float* __restrict__ outp)
{
    __shared__ float ts[4][HH];
    const int w = threadIdx.x >> 6;
    const int j = threadIdx.x & 63;
    const int n = blockIdx.x * 4 + w;
    const int rs = __builtin_amdgcn_readfirstlane(rowptr[n]);
    const int rc = __builtin_amdgcn_readfirstlane(cnt[n]);
    const int re = rs + rc;

    float acc = 0.0f;
    for (int k = rs; k < re; k += 8) {
        int2 pp[8];
        #pragma unroll
        for (int u = 0; u < 8; ++u) pp[u] = epack[k + u];     // may overrun into pad: fine
        float vv[8];
        #pragma unroll
        for (int u = 0; u < 8; ++u) vv[u] = bf2f(cur_in[(size_t)pp[u].x * HH + j]);
        #pragma unroll
        for (int u = 0; u < 8; ++u) {
            const float wgt = (k + u < re) ? __int_as_float(pp[u].y) : 0.0f;
            acc = fmaf(wgt, vv[u], acc);
        }
    }

    ts[w][j] = acc;                       // wave-private row: no barrier needed
    float z = degw[n] * bvec[j];
    #pragma unroll
    for (int q = 0; q < HH / 4; ++q) {
        const float4 t4 = ((const float4*)ts[w])[q];
        z = fmaf(t4.x, W[(4*q+0)*HH + j], z);
        z = fmaf(t4.y, W[(4*q+1)*HH + j], z);
        z = fmaf(t4.z, W[(4*q+2)*HH + j], z);
        z = fmaf(t4.w, W[(4*q+3)*HH + j], z);
    }
    const float r = fmaxf(z, 0.0f);
    const size_t o = (size_t)n * HH + j;
    if (!FINAL) {
        cur_out[o] = f2bf(r);
        hidden[o] += r * temp[tidx];
    } else {
        const float hid = hidden[o] + r * temp[tidx];
        ts[w][j] = hid;                   // reuse wave row for final projection
        float z2 = bout[j];
        #pragma unroll
        for (int q = 0; q < HH / 4; ++q) {
            const float4 t4 = ((const float4*)ts[w])[q];
            z2 = fmaf(t4.x, Wout[(4*q+0)*HH + j], z2);
            z2 = fmaf(t4.y, Wout[(4*q+1)*HH + j], z2);
            z2 = fmaf(t4.z, Wout[(4*q+2)*HH + j], z2);
            z2 = fmaf(t4.w, Wout[(4*q+3)*HH + j], z2);
        }
        outp[o] = z2;
    }
}

extern "C" void kernel_launch(void* const* d_in, const int* in_sizes, int n_in,
                              void* d_out, int out_size, void* d_ws, size_t ws_size,
                              hipStream_t stream)
{
    const float* x     = (const float*)d_in[0];
    const int*   ei    = (const int*)d_in[1];
    const float* ew    = (const float*)d_in[2];
    const float* W_in  = (const float*)d_in[3];
    const float* b_in  = (const float*)d_in[4];
    const float* LW    = (const float*)d_in[5];
    const float* Lb    = (const float*)d_in[6];
    const float* W_out = (const float*)d_in[7];
    const float* b_out = (const float*)d_in[8];
    const float* temp  = (const float*)d_in[9];
    const int* src = ei;
    const int* dst = ei + NE;

    char* p = (char*)d_ws;
    float*  hidden = (float*)p;   p += (size_t)NN * HH * 4;       // 12.8 MB
    ushort* h_bf   = (ushort*)p;  p += (size_t)NN * HH * 2;       // 6.4 MB
    ushort* curA   = (ushort*)p;  p += (size_t)NN * HH * 2;
    ushort* curB   = (ushort*)p;  p += (size_t)NN * HH * 2;
    int2*   epack  = (int2*)p;    p += (size_t)(NE + 8) * 8;      // 6.4 MB + pad
    u64*    packed = (u64*)p;     p += (size_t)NN * 8;            // 0.4 MB
    ushort* rank   = (ushort*)p;  p += (size_t)NE * 2;            // 1.6 MB
    int*    cnt    = (int*)p;     p += (size_t)NN * 4;
    float*  degw   = (float*)p;   p += (size_t)NN * 4;
    int*    rowptr = (int*)p;     p += (size_t)NN * 4;
    int*    bsum   = (int*)p;     p += 256 * 4;
    ushort* Wp     = (ushort*)p;  p += (size_t)CIN * HH * 2;      // 32 KB
    float*  out    = (float*)d_out;

    // packed histogram must start at zero
    hipMemsetAsync(packed, 0, (size_t)NN * 8, stream);
    // W_in -> bf16 MFMA B-fragment layout
    k_prepW<<<CIN * HH / 256, 256, 0, stream>>>(W_in, Wp);

    // hist (RMW-bound) fused with MFMA in-linear (L3-read-bound): they overlap
    k_inlin_hist<<<NHB + NGB, 256, 0, stream>>>(x, Wp, b_in, temp, dst, ew,
                                                packed, rank, h_bf, hidden);
    // prefix-scan counts -> rowptr; unpack degw
    k_scan1<<<NBLK, 256, 0, stream>>>(packed, cnt, degw, rowptr, bsum);
    k_scan2<<<1, 256, 0, stream>>>(bsum);
    k_scan3<<<NBLK, 256, 0, stream>>>(rowptr, bsum);
    // atomic-free counting-sort placement
    k_fill<<<NHB, 256, 0, stream>>>(src, dst, ew, rank, rowptr, epack);

    // 3 fused propagation layers; layer 3 also does the final projection
    k_layer<false><<<NN / 4, 256, 0, stream>>>(h_bf, curA, hidden, epack, rowptr, cnt, degw,
                                               LW + 0 * HH * HH, Lb + 0 * HH, temp, 1,
                                               nullptr, nullptr, nullptr);
    k_layer<false><<<NN / 4, 256, 0, stream>>>(curA, curB, hidden, epack, rowptr, cnt, degw,
                                               LW + 1 * HH * HH, Lb + 1 * HH, temp, 2,
                                               nullptr, nullptr, nullptr);
    k_layer<true><<<NN / 4, 256, 0, stream>>>(curB, nullptr, hidden, epack, rowptr, cnt, degw,
                                              LW + 2 * HH * HH, Lb + 2 * HH, temp, 3,
                                              W_out, b_out, out);
}

// Round 6
// 218.495 us; speedup vs baseline: 3.0059x; 1.0056x over previous
//
#include <hip/hip_runtime.h>
#include <hip/hip_bf16.h>

#define NN 50000
#define NE 800000
#define CIN 256
#define HH 64
#define NBLK 196          // ceil(NN/256) for scans
#define NHB 1563          // ceil((NE/2)/256) histogram blocks (2 edges/thread)
#define NEH 400000        // NE/2
#define NGB 782           // ceil(NN/64) GEMM blocks (64 rows each)
#define CHUNK 16
#define WSCALE 67108864.0f   // 2^26 fixed-point scale for edge weights
#define WMASK ((1ull << 42) - 1)

typedef unsigned long long u64;
typedef __attribute__((ext_vector_type(8))) short short8;
typedef __attribute__((ext_vector_type(4))) float f32x4;

__device__ __forceinline__ float bf2f(ushort u) {
    union { unsigned int i; float f; } v; v.i = ((unsigned int)u) << 16; return v.f;
}
__device__ __forceinline__ ushort f2bf(float f) {
    __hip_bfloat16 b = __float2bfloat16(f);   // RNE
    return *reinterpret_cast<ushort*>(&b);
}
__device__ __forceinline__ int rfl(int v) { return __builtin_amdgcn_readfirstlane(v); }

// ---------------- prep: W_in -> bf16, pre-swizzled into MFMA B-frag layout ---
__global__ __launch_bounds__(256) void k_prepW(
    const float* __restrict__ W, ushort* __restrict__ Wp)
{
    const int tid = blockIdx.x * 256 + threadIdx.x;   // 16384 total
    const int i = tid & 7;
    const int l = (tid >> 3) & 63;
    const int s = (tid >> 9) & 7;
    const int t = tid >> 12;
    const int k = s * 32 + (l >> 4) * 8 + i;
    const int c = t * 16 + (l & 15);
    Wp[tid] = f2bf(W[k * HH + c]);
}

// ---------------- fused: edge histogram (blocks < NHB) | MFMA in-linear ------
// Hist: 2 edges/thread (2 independent atomic chains in flight per lane).
// One packed u64 atomic per edge -> count (bits 42+), fixed-point weighted
// degree (bits 0..41); atomic return = rank of edge in its dst bucket.
__global__ __launch_bounds__(256) void k_inlin_hist(
    const float* __restrict__ x, const ushort* __restrict__ Wp,
    const float* __restrict__ b, const float* __restrict__ temp,
    const int* __restrict__ dst, const float* __restrict__ ew,
    u64* __restrict__ packed, ushort* __restrict__ rank,
    ushort* __restrict__ h_bf, float* __restrict__ hidden)
{
    if (blockIdx.x < NHB) {
        const int e0 = blockIdx.x * 256 + threadIdx.x;
        if (e0 < NEH) {
            const int e1 = e0 + NEH;
            const int d0 = dst[e0], d1 = dst[e1];
            const float w0 = ew[e0], w1 = ew[e1];
            const u64 inc0 = (1ull << 42) | (u64)(w0 * WSCALE + 0.5f);
            const u64 inc1 = (1ull << 42) | (u64)(w1 * WSCALE + 0.5f);
            const u64 o0 = atomicAdd(&packed[d0], inc0);
            const u64 o1 = atomicAdd(&packed[d1], inc1);
            rank[e0] = (ushort)(o0 >> 42);
            rank[e1] = (ushort)(o1 >> 42);
        }
        return;
    }
    const int w = threadIdx.x >> 6;          // wave 0..3
    const int l = threadIdx.x & 63;
    const int R0 = (blockIdx.x - NHB) * 64 + w * 16;
    const int arow = R0 + (l & 15);
    const int xrow = (arow < NN) ? arow : (NN - 1);
    const int kg = l >> 4;
    const float* xr = x + (size_t)xrow * CIN + kg * 8;
    const short8* WpV = (const short8*)Wp;

    f32x4 acc0 = {0,0,0,0}, acc1 = {0,0,0,0}, acc2 = {0,0,0,0}, acc3 = {0,0,0,0};
    #pragma unroll
    for (int s = 0; s < 8; ++s) {
        const float4 xa = *(const float4*)(xr + s * 32);
        const float4 xb = *(const float4*)(xr + s * 32 + 4);
        short8 af;
        af[0] = (short)f2bf(xa.x); af[1] = (short)f2bf(xa.y);
        af[2] = (short)f2bf(xa.z); af[3] = (short)f2bf(xa.w);
        af[4] = (short)f2bf(xb.x); af[5] = (short)f2bf(xb.y);
        af[6] = (short)f2bf(xb.z); af[7] = (short)f2bf(xb.w);
        acc0 = __builtin_amdgcn_mfma_f32_16x16x32_bf16(af, WpV[(0*8+s)*64 + l], acc0, 0, 0, 0);
        acc1 = __builtin_amdgcn_mfma_f32_16x16x32_bf16(af, WpV[(1*8+s)*64 + l], acc1, 0, 0, 0);
        acc2 = __builtin_amdgcn_mfma_f32_16x16x32_bf16(af, WpV[(2*8+s)*64 + l], acc2, 0, 0, 0);
        acc3 = __builtin_amdgcn_mfma_f32_16x16x32_bf16(af, WpV[(3*8+s)*64 + l], acc3, 0, 0, 0);
    }
    const float t0v = temp[0];
    const int colb = l & 15;
    const int rbase = R0 + (l >> 4) * 4;
    #pragma unroll
    for (int t = 0; t < 4; ++t) {
        const f32x4 a = (t == 0) ? acc0 : (t == 1) ? acc1 : (t == 2) ? acc2 : acc3;
        const float bb = b[t * 16 + colb];
        #pragma unroll
        for (int r = 0; r < 4; ++r) {
            const int row = rbase + r;
            if (row < NN) {
                const float v = a[r] + bb;
                const size_t o = (size_t)row * HH + t * 16 + colb;
                h_bf[o]   = f2bf(v);
                hidden[o] = v * t0v;
            }
        }
    }
}

// ---------------- scans: unpack + exclusive prefix over counts ---------------
__global__ __launch_bounds__(256) void k_scan1(
    const u64* __restrict__ packed, int* __restrict__ cnt, float* __restrict__ degw,
    int* __restrict__ rowptr, int* __restrict__ bsum)
{
    __shared__ int s[256];
    const int t = threadIdx.x;
    const int i = blockIdx.x * 256 + t;
    int v = 0;
    if (i < NN) {
        const u64 pk = packed[i];
        v = (int)(pk >> 42);
        cnt[i] = v;
        degw[i] = (float)(pk & WMASK) * (1.0f / WSCALE);
    }
    s[t] = v; __syncthreads();
    #pragma unroll
    for (int off = 1; off < 256; off <<= 1) {
        const int add = (t >= off) ? s[t - off] : 0;
        __syncthreads();
        s[t] += add;
        __syncthreads();
    }
    if (i < NN) rowptr[i] = s[t] - v;
    if (t == 255) bsum[blockIdx.x] = s[t];
}

__global__ __launch_bounds__(256) void k_scan2(int* __restrict__ bsum)
{
    __shared__ int s[256];
    const int t = threadIdx.x;
    const int v = (t < NBLK) ? bsum[t] : 0;
    s[t] = v; __syncthreads();
    #pragma unroll
    for (int off = 1; off < 256; off <<= 1) {
        const int add = (t >= off) ? s[t - off] : 0;
        __syncthreads();
        s[t] += add;
        __syncthreads();
    }
    if (t < NBLK) bsum[t] = s[t] - v;
}

__global__ __launch_bounds__(256) void k_scan3(
    int* __restrict__ rowptr, const int* __restrict__ bsum)
{
    const int i = blockIdx.x * 256 + threadIdx.x;
    if (i < NN) rowptr[i] += bsum[blockIdx.x];
}

// ---------------- fill: counting-sort placement, NO atomics ------------------
__global__ __launch_bounds__(256) void k_fill(
    const int* __restrict__ src, const int* __restrict__ dst,
    const float* __restrict__ ew, const ushort* __restrict__ rank,
    const int* __restrict__ rowptr, int2* __restrict__ epack)
{
    const int e = blockIdx.x * 256 + threadIdx.x;   // grid = NE/256 exact
    if (blockIdx.x == 0 && threadIdx.x < CHUNK)
        epack[NE + threadIdx.x] = make_int2(0, 0);  // pad for masked chunks
    const int d = dst[e];
    const int pos = rowptr[d] + (int)rank[e];
    epack[pos] = make_int2(src[e], __float_as_int(ew[e]));
}

// ---------------- fused layer -------------------------------------------------
// Per node n (one wave, lane j = channel): 16-deep masked gather chunks with
// double-buffered, scalarized (SGPR) edge metadata -> 16 gathers in flight,
// epack latency hidden behind previous chunk. Then 64x64 matvec via LDS row.
template<bool FINAL>
__global__ __launch_bounds__(256) void k_layer(
    const ushort* __restrict__ cur_in, ushort* __restrict__ cur_out,
    float* __restrict__ hidden,
    const int2* __restrict__ epack, const int* __restrict__ rowptr,
    const int* __restrict__ cnt, const float* __restrict__ degw,
    const float* __restrict__ W, const float* __restrict__ bvec,
    const float* __restrict__ temp, int tidx,
    const float* __restrict__ Wout, const float* __restrict__ bout,
    float* __restrict__ outp)
{
    __shared__ float ts[4][HH];
    const int w = threadIdx.x >> 6;
    const int j = threadIdx.x & 63;
    const int n = blockIdx.x * 4 + w;
    const int rs = rfl(rowptr[n]);
    const int rc = rfl(cnt[n]);
    const int re = rs + rc;

    float acc = 0.0f;
    int   nx[CHUNK];
    float nw[CHUNK];
    // prefetch first chunk metadata (scalarized: wave-uniform)
    #pragma unroll
    for (int u = 0; u < CHUNK; ++u) {
        const int2 p = epack[rs + u];               // pad makes this in-bounds
        nx[u] = rfl(p.x);
        nw[u] = (rs + u < re) ? __int_as_float(rfl(p.y)) : 0.0f;
    }
    for (int k = rs; k < re; k += CHUNK) {
        int   cx[CHUNK];
        float cw[CHUNK];
        #pragma unroll
        for (int u = 0; u < CHUNK; ++u) { cx[u] = nx[u]; cw[u] = nw[u]; }
        // issue all 16 gathers (saddr-form: SGPR row base + lane offset)
        float vv[CHUNK];
        #pragma unroll
        for (int u = 0; u < CHUNK; ++u)
            vv[u] = bf2f(cur_in[(size_t)cx[u] * HH + j]);
        // prefetch next chunk metadata while gathers are in flight
        const int k2 = k + CHUNK;
        if (k2 < re) {
            #pragma unroll
            for (int u = 0; u < CHUNK; ++u) {
                const int2 p = epack[k2 + u];
                nx[u] = rfl(p.x);
                nw[u] = (k2 + u < re) ? __int_as_float(rfl(p.y)) : 0.0f;
            }
        }
        #pragma unroll
        for (int u = 0; u < CHUNK; ++u)
            acc = fmaf(cw[u], vv[u], acc);
    }

    ts[w][j] = acc;                       // wave-private row: no barrier needed
    float z = degw[n] * bvec[j];
    #pragma unroll
    for (int q = 0; q < HH / 4; ++q) {
        const float4 t4 = ((const float4*)ts[w])[q];
        z = fmaf(t4.x, W[(4*q+0)*HH + j], z);
        z = fmaf(t4.y, W[(4*q+1)*HH + j], z);
        z = fmaf(t4.z, W[(4*q+2)*HH + j], z);
        z = fmaf(t4.w, W[(4*q+3)*HH + j], z);
    }
    const float r = fmaxf(z, 0.0f);
    const size_t o = (size_t)n * HH + j;
    if (!FINAL) {
        cur_out[o] = f2bf(r);
        hidden[o] += r * temp[tidx];
    } else {
        const float hid = hidden[o] + r * temp[tidx];
        ts[w][j] = hid;                   // reuse wave row for final projection
        float z2 = bout[j];
        #pragma unroll
        for (int q = 0; q < HH / 4; ++q) {
            const float4 t4 = ((const float4*)ts[w])[q];
            z2 = fmaf(t4.x, Wout[(4*q+0)*HH + j], z2);
            z2 = fmaf(t4.y, Wout[(4*q+1)*HH + j], z2);
            z2 = fmaf(t4.z, Wout[(4*q+2)*HH + j], z2);
            z2 = fmaf(t4.w, Wout[(4*q+3)*HH + j], z2);
        }
        outp[o] = z2;
    }
}

extern "C" void kernel_launch(void* const* d_in, const int* in_sizes, int n_in,
                              void* d_out, int out_size, void* d_ws, size_t ws_size,
                              hipStream_t stream)
{
    const float* x     = (const float*)d_in[0];
    const int*   ei    = (const int*)d_in[1];
    const float* ew    = (const float*)d_in[2];
    const float* W_in  = (const float*)d_in[3];
    const float* b_in  = (const float*)d_in[4];
    const float* LW    = (const float*)d_in[5];
    const float* Lb    = (const float*)d_in[6];
    const float* W_out = (const float*)d_in[7];
    const float* b_out = (const float*)d_in[8];
    const float* temp  = (const float*)d_in[9];
    const int* src = ei;
    const int* dst = ei + NE;

    char* p = (char*)d_ws;
    float*  hidden = (float*)p;   p += (size_t)NN * HH * 4;       // 12.8 MB
    ushort* h_bf   = (ushort*)p;  p += (size_t)NN * HH * 2;       // 6.4 MB
    ushort* curA   = (ushort*)p;  p += (size_t)NN * HH * 2;
    ushort* curB   = (ushort*)p;  p += (size_t)NN * HH * 2;
    int2*   epack  = (int2*)p;    p += (size_t)(NE + CHUNK) * 8;  // 6.4 MB + pad
    u64*    packed = (u64*)p;     p += (size_t)NN * 8;            // 0.4 MB
    ushort* rank   = (ushort*)p;  p += (size_t)NE * 2;            // 1.6 MB
    int*    cnt    = (int*)p;     p += (size_t)NN * 4;
    float*  degw   = (float*)p;   p += (size_t)NN * 4;
    int*    rowptr = (int*)p;     p += (size_t)NN * 4;
    int*    bsum   = (int*)p;     p += 256 * 4;
    ushort* Wp     = (ushort*)p;  p += (size_t)CIN * HH * 2;      // 32 KB
    float*  out    = (float*)d_out;

    // packed histogram must start at zero
    hipMemsetAsync(packed, 0, (size_t)NN * 8, stream);
    // W_in -> bf16 MFMA B-fragment layout
    k_prepW<<<CIN * HH / 256, 256, 0, stream>>>(W_in, Wp);

    // hist (RMW-bound) fused with MFMA in-linear: they overlap
    k_inlin_hist<<<NHB + NGB, 256, 0, stream>>>(x, Wp, b_in, temp, dst, ew,
                                                packed, rank, h_bf, hidden);
    // prefix-scan counts -> rowptr; unpack degw
    k_scan1<<<NBLK, 256, 0, stream>>>(packed, cnt, degw, rowptr, bsum);
    k_scan2<<<1, 256, 0, stream>>>(bsum);
    k_scan3<<<NBLK, 256, 0, stream>>>(rowptr, bsum);
    // atomic-free counting-sort placement
    k_fill<<<NE / 256, 256, 0, stream>>>(src, dst, ew, rank, rowptr, epack);

    // 3 fused propagation layers; layer 3 also does the final projection
    k_layer<false><<<NN / 4, 256, 0, stream>>>(h_bf, curA, hidden, epack, rowptr, cnt, degw,
                                               LW + 0 * HH * HH, Lb + 0 * HH, temp, 1,
                                               nullptr, nullptr, nullptr);
    k_layer<false><<<NN / 4, 256, 0, stream>>>(curA, curB, hidden, epack, rowptr, cnt, degw,
                                               LW + 1 * HH * HH, Lb + 1 * HH, temp, 2,
                                               nullptr, nullptr, nullptr);
    k_layer<true><<<NN / 4, 256, 0, stream>>>(curB, nullptr, hidden, epack, rowptr, cnt, degw,
                                              LW + 2 * HH * HH, Lb + 2 * HH, temp, 3,
                                              W_out, b_out, out);
}

// Round 7
// 175.946 us; speedup vs baseline: 3.7329x; 1.2418x over previous
//
#include <hip/hip_runtime.h>
#include <hip/hip_bf16.h>

#define NN 50000
#define NE 800000
#define CIN 256
#define HH 64
#define NBLK 196          // ceil(NN/256) for scans
#define NHB 1563          // ceil((NE/2)/256) histogram blocks (2 edges/thread)
#define NEH 400000        // NE/2
#define NGB 782           // ceil(NN/64) GEMM blocks (64 rows each)
#define NLB 3125          // NN/16 layer blocks (16 nodes each)
#define WSCALE 67108864.0f   // 2^26 fixed-point scale for edge weights
#define WMASK ((1ull << 42) - 1)

typedef unsigned long long u64;
typedef __attribute__((ext_vector_type(8))) short short8;
typedef __attribute__((ext_vector_type(4))) float f32x4;

__device__ __forceinline__ float bf2f(ushort u) {
    union { unsigned int i; float f; } v; v.i = ((unsigned int)u) << 16; return v.f;
}
__device__ __forceinline__ ushort f2bf(float f) {
    __hip_bfloat16 b = __float2bfloat16(f);   // RNE
    return *reinterpret_cast<ushort*>(&b);
}

// ---------------- prep: all weights -> bf16 MFMA B-frag layout ---------------
// W_in (K=256): Wp[((t*8+s)*64+l)*8+i] = W[k=s*32+(l>>4)*8+i][c=t*16+(l&15)]
// LW0,LW1,LW2,W_out (K=64): Wp[16384 + m*4096 + ((t*2+s)*64+l)*8+i]
__global__ __launch_bounds__(256) void k_prep(
    const float* __restrict__ W_in, const float* __restrict__ LW,
    const float* __restrict__ W_out, ushort* __restrict__ Wp)
{
    const int tid = blockIdx.x * 256 + threadIdx.x;   // 32768 total
    if (tid < 16384) {
        const int i = tid & 7;
        const int l = (tid >> 3) & 63;
        const int s = (tid >> 9) & 7;
        const int t = tid >> 12;
        const int k = s * 32 + (l >> 4) * 8 + i;
        const int c = t * 16 + (l & 15);
        Wp[tid] = f2bf(W_in[k * HH + c]);
    } else {
        const int q = (tid - 16384) & 4095;
        const int m = (tid - 16384) >> 12;            // 0..3
        const int i = q & 7;
        const int l = (q >> 3) & 63;
        const int s = (q >> 9) & 1;
        const int t = q >> 10;
        const int k = s * 32 + (l >> 4) * 8 + i;
        const int c = t * 16 + (l & 15);
        const float* Wm = (m < 3) ? (LW + m * HH * HH) : W_out;
        Wp[tid] = f2bf(Wm[k * HH + c]);
    }
}

// ---------------- fused: edge histogram (blocks < NHB) | MFMA in-linear ------
__global__ __launch_bounds__(256) void k_inlin_hist(
    const float* __restrict__ x, const ushort* __restrict__ Wp,
    const float* __restrict__ b,
    const int* __restrict__ dst, const float* __restrict__ ew,
    u64* __restrict__ packed, ushort* __restrict__ rank,
    ushort* __restrict__ h_bf)
{
    if (blockIdx.x < NHB) {
        const int e0 = blockIdx.x * 256 + threadIdx.x;
        if (e0 < NEH) {
            const int e1 = e0 + NEH;
            const int d0 = dst[e0], d1 = dst[e1];
            const u64 inc0 = (1ull << 42) | (u64)(ew[e0] * WSCALE + 0.5f);
            const u64 inc1 = (1ull << 42) | (u64)(ew[e1] * WSCALE + 0.5f);
            const u64 o0 = atomicAdd(&packed[d0], inc0);
            const u64 o1 = atomicAdd(&packed[d1], inc1);
            rank[e0] = (ushort)(o0 >> 42);
            rank[e1] = (ushort)(o1 >> 42);
        }
        return;
    }
    const int w = threadIdx.x >> 6;          // wave 0..3
    const int l = threadIdx.x & 63;
    const int R0 = (blockIdx.x - NHB) * 64 + w * 16;
    const int arow = R0 + (l & 15);
    const int xrow = (arow < NN) ? arow : (NN - 1);
    const float* xr = x + (size_t)xrow * CIN + (l >> 4) * 8;
    const short8* WpV = (const short8*)Wp;

    f32x4 acc0 = {0,0,0,0}, acc1 = {0,0,0,0}, acc2 = {0,0,0,0}, acc3 = {0,0,0,0};
    #pragma unroll
    for (int s = 0; s < 8; ++s) {
        const float4 xa = *(const float4*)(xr + s * 32);
        const float4 xb = *(const float4*)(xr + s * 32 + 4);
        short8 af;
        af[0] = (short)f2bf(xa.x); af[1] = (short)f2bf(xa.y);
        af[2] = (short)f2bf(xa.z); af[3] = (short)f2bf(xa.w);
        af[4] = (short)f2bf(xb.x); af[5] = (short)f2bf(xb.y);
        af[6] = (short)f2bf(xb.z); af[7] = (short)f2bf(xb.w);
        acc0 = __builtin_amdgcn_mfma_f32_16x16x32_bf16(af, WpV[(0*8+s)*64 + l], acc0, 0, 0, 0);
        acc1 = __builtin_amdgcn_mfma_f32_16x16x32_bf16(af, WpV[(1*8+s)*64 + l], acc1, 0, 0, 0);
        acc2 = __builtin_amdgcn_mfma_f32_16x16x32_bf16(af, WpV[(2*8+s)*64 + l], acc2, 0, 0, 0);
        acc3 = __builtin_amdgcn_mfma_f32_16x16x32_bf16(af, WpV[(3*8+s)*64 + l], acc3, 0, 0, 0);
    }
    const int colb = l & 15;
    const int rbase = R0 + (l >> 4) * 4;
    #pragma unroll
    for (int t = 0; t < 4; ++t) {
        const f32x4 a = (t == 0) ? acc0 : (t == 1) ? acc1 : (t == 2) ? acc2 : acc3;
        const float bb = b[t * 16 + colb];
        #pragma unroll
        for (int r = 0; r < 4; ++r) {
            const int row = rbase + r;
            if (row < NN)
                h_bf[(size_t)row * HH + t * 16 + colb] = f2bf(a[r] + bb);
        }
    }
}

// ---------------- scans ------------------------------------------------------
__global__ __launch_bounds__(256) void k_scan1(
    const u64* __restrict__ packed, int* __restrict__ cnt, float* __restrict__ degw,
    int* __restrict__ rowptr, int* __restrict__ bsum)
{
    __shared__ int s[256];
    const int t = threadIdx.x;
    const int i = blockIdx.x * 256 + t;
    int v = 0;
    if (i < NN) {
        const u64 pk = packed[i];
        v = (int)(pk >> 42);
        cnt[i] = v;
        degw[i] = (float)(pk & WMASK) * (1.0f / WSCALE);
    }
    s[t] = v; __syncthreads();
    #pragma unroll
    for (int off = 1; off < 256; off <<= 1) {
        const int add = (t >= off) ? s[t - off] : 0;
        __syncthreads();
        s[t] += add;
        __syncthreads();
    }
    if (i < NN) rowptr[i] = s[t] - v;
    if (t == 255) bsum[blockIdx.x] = s[t];
}

__global__ __launch_bounds__(256) void k_scan2(int* __restrict__ bsum)
{
    __shared__ int s[256];
    const int t = threadIdx.x;
    const int v = (t < NBLK) ? bsum[t] : 0;
    s[t] = v; __syncthreads();
    #pragma unroll
    for (int off = 1; off < 256; off <<= 1) {
        const int add = (t >= off) ? s[t - off] : 0;
        __syncthreads();
        s[t] += add;
        __syncthreads();
    }
    if (t < NBLK) bsum[t] = s[t] - v;
}

__global__ __launch_bounds__(256) void k_scan3(
    int* __restrict__ rowptr, const int* __restrict__ bsum)
{
    const int i = blockIdx.x * 256 + threadIdx.x;
    if (i < NN) rowptr[i] += bsum[blockIdx.x];
}

// ---------------- fill: counting-sort placement, NO atomics ------------------
// Uses partial rowptr + bsum directly so it doesn't wait on scan3.
__global__ __launch_bounds__(256) void k_fill(
    const int* __restrict__ src, const int* __restrict__ dst,
    const float* __restrict__ ew, const ushort* __restrict__ rank,
    const int* __restrict__ rowptrP, const int* __restrict__ bsum,
    int2* __restrict__ epack)
{
    const int e = blockIdx.x * 256 + threadIdx.x;   // exact grid
    const int d = dst[e];
    const int pos = rowptrP[d] + bsum[d >> 8] + (int)rank[e];
    epack[pos] = make_int2(src[e], __float_as_int(ew[e]));
}

// ---------------- fused layer: block = 16 nodes, 4 waves ---------------------
// Gather phase (per wave, 4 nodes): lane-parallel epack load -> LDS, then
// clamp-masked 16-groups of bf16 gathers (masked slots dup a valid line).
// MFMA phase: 64x64 linear via 2 MFMAs/wave (pre-swizzled B-frags).
// FINAL: hidden = t0*h + t1*c1 + t2*c2 + t3*relu -> second MFMA @ W_out.
template<bool FINAL>
__global__ __launch_bounds__(256) void k_layer(
    const ushort* __restrict__ cur_in, ushort* __restrict__ cur_out,
    const int2* __restrict__ epack, const int* __restrict__ rowptr,
    const int* __restrict__ cnt, const float* __restrict__ degw,
    const ushort* __restrict__ WpL, const float* __restrict__ bvec,
    const float* __restrict__ temp,
    const ushort* __restrict__ hbf, const ushort* __restrict__ c1,
    const ushort* __restrict__ WpO, const float* __restrict__ bout,
    float* __restrict__ outp)
{
    __shared__ int2  es[4][64];
    __shared__ ushort ts[16][72];      // padded: bank-even b128 reads
    const int w = threadIdx.x >> 6;
    const int j = threadIdx.x & 63;
    const int nb = blockIdx.x * 16;

    // ---- gather-aggregate: wave w handles nodes nb + w*4 + q ----
    #pragma unroll
    for (int q = 0; q < 4; ++q) {
        const int n  = nb + w * 4 + q;
        const int rs = rowptr[n];
        const int rc = cnt[n];
        float acc = 0.0f;
        for (int base = 0; base < rc; base += 64) {
            const int m = min(rc - base, 64);
            if (j < m) es[w][j] = epack[rs + base + j];
            for (int g = 0; g < m; g += 16) {
                float vv[16], ww[16];
                #pragma unroll
                for (int u = 0; u < 16; ++u) {
                    const int idx = g + u;
                    const int sel = (idx < m) ? idx : 0;   // clamp: dup line, cheap
                    const int2 p = es[w][sel];             // LDS broadcast read
                    ww[u] = (idx < m) ? __int_as_float(p.y) : 0.0f;
                    vv[u] = bf2f(cur_in[(size_t)p.x * HH + j]);
                }
                #pragma unroll
                for (int u = 0; u < 16; ++u) acc = fmaf(ww[u], vv[u], acc);
            }
        }
        ts[w * 4 + q][j] = f2bf(acc);
    }
    __syncthreads();

    // ---- MFMA: wave w computes output cols [w*16, w*16+16) for 16 nodes ----
    const int lr = j & 15;             // within-tile col
    const int lg = j >> 4;             // reg group
    const short8 a0 = *(const short8*)&ts[lr][lg * 8];
    const short8 a1 = *(const short8*)&ts[lr][32 + lg * 8];
    if (FINAL) __syncthreads();        // all A-frags read before ts is reused

    const short8* WpV = (const short8*)WpL;
    f32x4 zac = {0,0,0,0};
    zac = __builtin_amdgcn_mfma_f32_16x16x32_bf16(a0, WpV[(w*2+0)*64 + j], zac, 0, 0, 0);
    zac = __builtin_amdgcn_mfma_f32_16x16x32_bf16(a1, WpV[(w*2+1)*64 + j], zac, 0, 0, 0);

    const float bb = bvec[w * 16 + lr];
    float t0v = 0, t1v = 0, t2v = 0, t3v = 0;
    if (FINAL) { t0v = temp[0]; t1v = temp[1]; t2v = temp[2]; t3v = temp[3]; }
    #pragma unroll
    for (int r = 0; r < 4; ++r) {
        const int row = lg * 4 + r;    // local node
        const int n   = nb + row;
        const float z = zac[r] + degw[n] * bb;
        const float rv = fmaxf(z, 0.0f);
        const size_t o = (size_t)n * HH + w * 16 + lr;
        if (!FINAL) {
            cur_out[o] = f2bf(rv);
        } else {
            const float hid = t0v * bf2f(hbf[o]) + t1v * bf2f(c1[o])
                            + t2v * bf2f(cur_in[o]) + t3v * rv;
            ts[row][w * 16 + lr] = f2bf(hid);
        }
    }
    if (FINAL) {
        __syncthreads();
        const short8 b0 = *(const short8*)&ts[lr][lg * 8];
        const short8 b1 = *(const short8*)&ts[lr][32 + lg * 8];
        const short8* WoV = (const short8*)WpO;
        f32x4 oz = {0,0,0,0};
        oz = __builtin_amdgcn_mfma_f32_16x16x32_bf16(b0, WoV[(w*2+0)*64 + j], oz, 0, 0, 0);
        oz = __builtin_amdgcn_mfma_f32_16x16x32_bf16(b1, WoV[(w*2+1)*64 + j], oz, 0, 0, 0);
        const float bo = bout[w * 16 + lr];
        #pragma unroll
        for (int r = 0; r < 4; ++r) {
            const int row = lg * 4 + r;
            outp[(size_t)(nb + row) * HH + w * 16 + lr] = oz[r] + bo;
        }
    }
}

extern "C" void kernel_launch(void* const* d_in, const int* in_sizes, int n_in,
                              void* d_out, int out_size, void* d_ws, size_t ws_size,
                              hipStream_t stream)
{
    const float* x     = (const float*)d_in[0];
    const int*   ei    = (const int*)d_in[1];
    const float* ew    = (const float*)d_in[2];
    const float* W_in  = (const float*)d_in[3];
    const float* b_in  = (const float*)d_in[4];
    const float* LW    = (const float*)d_in[5];
    const float* Lb    = (const float*)d_in[6];
    const float* W_out = (const float*)d_in[7];
    const float* b_out = (const float*)d_in[8];
    const float* temp  = (const float*)d_in[9];
    const int* src = ei;
    const int* dst = ei + NE;

    char* p = (char*)d_ws;
    ushort* h_bf   = (ushort*)p;  p += (size_t)NN * HH * 2;       // 6.4 MB
    ushort* curA   = (ushort*)p;  p += (size_t)NN * HH * 2;
    ushort* curB   = (ushort*)p;  p += (size_t)NN * HH * 2;
    int2*   epack  = (int2*)p;    p += (size_t)NE * 8;            // 6.4 MB
    u64*    packed = (u64*)p;     p += (size_t)NN * 8;            // 0.4 MB
    ushort* rank   = (ushort*)p;  p += (size_t)NE * 2;            // 1.6 MB
    int*    cnt    = (int*)p;     p += (size_t)NN * 4;
    float*  degw   = (float*)p;   p += (size_t)NN * 4;
    int*    rowptr = (int*)p;     p += (size_t)NN * 4;
    int*    bsum   = (int*)p;     p += 256 * 4;
    ushort* Wp     = (ushort*)p;  p += 32768 * 2;                 // 64 KB
    float*  out    = (float*)d_out;

    const ushort* WpIn  = Wp;
    const ushort* WpL0  = Wp + 16384;
    const ushort* WpL1  = Wp + 16384 + 4096;
    const ushort* WpL2  = Wp + 16384 + 2 * 4096;
    const ushort* WpOut = Wp + 16384 + 3 * 4096;

    hipMemsetAsync(packed, 0, (size_t)NN * 8, stream);
    k_prep<<<128, 256, 0, stream>>>(W_in, LW, W_out, Wp);

    // hist (RMW-bound) fused with MFMA in-linear: they overlap
    k_inlin_hist<<<NHB + NGB, 256, 0, stream>>>(x, WpIn, b_in, dst, ew,
                                                packed, rank, h_bf);
    k_scan1<<<NBLK, 256, 0, stream>>>(packed, cnt, degw, rowptr, bsum);
    k_scan2<<<1, 256, 0, stream>>>(bsum);
    k_fill<<<NE / 256, 256, 0, stream>>>(src, dst, ew, rank, rowptr, bsum, epack);
    k_scan3<<<NBLK, 256, 0, stream>>>(rowptr, bsum);   // finalize rowptr for layers

    // 3 fused propagation layers; FINAL recomputes hidden from bf16 terms
    k_layer<false><<<NLB, 256, 0, stream>>>(h_bf, curA, epack, rowptr, cnt, degw,
                                            WpL0, Lb + 0 * HH, temp,
                                            nullptr, nullptr, nullptr, nullptr, nullptr);
    k_layer<false><<<NLB, 256, 0, stream>>>(curA, curB, epack, rowptr, cnt, degw,
                                            WpL1, Lb + 1 * HH, temp,
                                            nullptr, nullptr, nullptr, nullptr, nullptr);
    k_layer<true><<<NLB, 256, 0, stream>>>(curB, nullptr, epack, rowptr, cnt, degw,
                                           WpL2, Lb + 2 * HH, temp,
                                           h_bf, curA, WpOut, b_out, out);
}

// Round 8
// 163.272 us; speedup vs baseline: 4.0226x; 1.0776x over previous
//
#include <hip/hip_runtime.h>
#include <hip/hip_bf16.h>

#define NN 50000
#define NE 800000
#define CIN 256
#define HH 64
#define NBINS 196         // dst>>8 buckets (50000/256)
#define B1 256            // pass-A blocks
#define EPB 3125          // edges per pass-A block (B1*EPB == NE)
#define NGB 782           // ceil(NN/64) GEMM blocks (64 rows each)
#define NLB 3125          // NN/16 layer blocks (16 nodes each)

typedef unsigned long long u64;
typedef __attribute__((ext_vector_type(8))) short short8;
typedef __attribute__((ext_vector_type(4))) float f32x4;

__device__ __forceinline__ float bf2f(ushort u) {
    union { unsigned int i; float f; } v; v.i = ((unsigned int)u) << 16; return v.f;
}
__device__ __forceinline__ ushort f2bf(float f) {
    __hip_bfloat16 b = __float2bfloat16(f);   // RNE
    return *reinterpret_cast<ushort*>(&b);
}

// ---------------- prep: all weights -> bf16 MFMA B-frag layout ---------------
__global__ __launch_bounds__(256) void k_prep(
    const float* __restrict__ W_in, const float* __restrict__ LW,
    const float* __restrict__ W_out, ushort* __restrict__ Wp)
{
    const int tid = blockIdx.x * 256 + threadIdx.x;   // 32768 total
    if (tid < 16384) {
        const int i = tid & 7;
        const int l = (tid >> 3) & 63;
        const int s = (tid >> 9) & 7;
        const int t = tid >> 12;
        const int k = s * 32 + (l >> 4) * 8 + i;
        const int c = t * 16 + (l & 15);
        Wp[tid] = f2bf(W_in[k * HH + c]);
    } else {
        const int q = (tid - 16384) & 4095;
        const int m = (tid - 16384) >> 12;            // 0..3
        const int i = q & 7;
        const int l = (q >> 3) & 63;
        const int s = (q >> 9) & 1;
        const int t = q >> 10;
        const int k = s * 32 + (l >> 4) * 8 + i;
        const int c = t * 16 + (l & 15);
        const float* Wm = (m < 3) ? (LW + m * HH * HH) : W_out;
        Wp[tid] = f2bf(Wm[k * HH + c]);
    }
}

// ------- fused: pass-A LDS histogram (blocks < B1) | MFMA in-linear ----------
__global__ __launch_bounds__(256) void k_fused(
    const float* __restrict__ x, const ushort* __restrict__ Wp,
    const float* __restrict__ b, const int* __restrict__ dst,
    int* __restrict__ H, ushort* __restrict__ h_bf)
{
    __shared__ int hist[NBINS];
    if (blockIdx.x < B1) {
        for (int t = threadIdx.x; t < NBINS; t += 256) hist[t] = 0;
        __syncthreads();
        const int e0 = blockIdx.x * EPB;
        for (int i = threadIdx.x; i < EPB; i += 256)
            atomicAdd(&hist[dst[e0 + i] >> 8], 1);
        __syncthreads();
        for (int t = threadIdx.x; t < NBINS; t += 256)
            H[t * B1 + blockIdx.x] = hist[t];
        return;
    }
    const int w = threadIdx.x >> 6;          // wave 0..3
    const int l = threadIdx.x & 63;
    const int R0 = (blockIdx.x - B1) * 64 + w * 16;
    const int arow = R0 + (l & 15);
    const int xrow = (arow < NN) ? arow : (NN - 1);
    const float* xr = x + (size_t)xrow * CIN + (l >> 4) * 8;
    const short8* WpV = (const short8*)Wp;

    f32x4 acc0 = {0,0,0,0}, acc1 = {0,0,0,0}, acc2 = {0,0,0,0}, acc3 = {0,0,0,0};
    #pragma unroll
    for (int s = 0; s < 8; ++s) {
        const float4 xa = *(const float4*)(xr + s * 32);
        const float4 xb = *(const float4*)(xr + s * 32 + 4);
        short8 af;
        af[0] = (short)f2bf(xa.x); af[1] = (short)f2bf(xa.y);
        af[2] = (short)f2bf(xa.z); af[3] = (short)f2bf(xa.w);
        af[4] = (short)f2bf(xb.x); af[5] = (short)f2bf(xb.y);
        af[6] = (short)f2bf(xb.z); af[7] = (short)f2bf(xb.w);
        acc0 = __builtin_amdgcn_mfma_f32_16x16x32_bf16(af, WpV[(0*8+s)*64 + l], acc0, 0, 0, 0);
        acc1 = __builtin_amdgcn_mfma_f32_16x16x32_bf16(af, WpV[(1*8+s)*64 + l], acc1, 0, 0, 0);
        acc2 = __builtin_amdgcn_mfma_f32_16x16x32_bf16(af, WpV[(2*8+s)*64 + l], acc2, 0, 0, 0);
        acc3 = __builtin_amdgcn_mfma_f32_16x16x32_bf16(af, WpV[(3*8+s)*64 + l], acc3, 0, 0, 0);
    }
    const int colb = l & 15;
    const int rbase = R0 + (l >> 4) * 4;
    #pragma unroll
    for (int t = 0; t < 4; ++t) {
        const f32x4 a = (t == 0) ? acc0 : (t == 1) ? acc1 : (t == 2) ? acc2 : acc3;
        const float bb = b[t * 16 + colb];
        #pragma unroll
        for (int r = 0; r < 4; ++r) {
            const int row = rbase + r;
            if (row < NN)
                h_bf[(size_t)row * HH + t * 16 + colb] = f2bf(a[r] + bb);
        }
    }
}

// ------- scanH: in-place exclusive scan of H (bin-major), bucket bases -------
__global__ __launch_bounds__(256) void k_scanH(
    int* __restrict__ H, int* __restrict__ Sx, int* __restrict__ bcnt)
{
    __shared__ int s[256];
    const int t = threadIdx.x;
    int rowsum = 0;
    if (t < NBINS) {
        const int4* row = (const int4*)(H + t * B1);
        #pragma unroll 8
        for (int c = 0; c < B1 / 4; ++c) {
            const int4 v = row[c];
            rowsum += v.x + v.y + v.z + v.w;
        }
    }
    s[t] = (t < NBINS) ? rowsum : 0;
    __syncthreads();
    #pragma unroll
    for (int off = 1; off < 256; off <<= 1) {
        const int add = (t >= off) ? s[t - off] : 0;
        __syncthreads();
        s[t] += add;
        __syncthreads();
    }
    if (t < NBINS) {
        const int rowstart = s[t] - rowsum;
        Sx[t] = rowstart;
        bcnt[t] = rowsum;
        int run = rowstart;
        int4* row = (int4*)(H + t * B1);
        for (int c = 0; c < B1 / 4; ++c) {
            int4 v = row[c];
            int4 o;
            o.x = run; run += v.x;
            o.y = run; run += v.y;
            o.z = run; run += v.z;
            o.w = run; run += v.w;
            row[c] = o;
        }
    }
}

// ------- scatterA: place edges into dst-high buckets (LDS cursors only) ------
__global__ __launch_bounds__(256) void k_scatterA(
    const int* __restrict__ src, const int* __restrict__ dst,
    const float* __restrict__ ew, const int* __restrict__ H,
    int2* __restrict__ tmp_e, ushort* __restrict__ tmp_low)
{
    __shared__ int cur[NBINS];
    for (int t = threadIdx.x; t < NBINS; t += 256)
        cur[t] = H[t * B1 + blockIdx.x];
    __syncthreads();
    const int e0 = blockIdx.x * EPB;
    for (int i = threadIdx.x; i < EPB; i += 256) {
        const int e = e0 + i;
        const int d = dst[e];
        const int pos = atomicAdd(&cur[d >> 8], 1);
        tmp_e[pos] = make_int2(src[e], __float_as_int(ew[e]));
        tmp_low[pos] = (ushort)(d & 255);
    }
}

// ------- sortB: per high-bucket LSD pass -> epack, rowptr, cnt ---------------
__global__ __launch_bounds__(512) void k_sortB(
    const int2* __restrict__ tmp_e, const ushort* __restrict__ tmp_low,
    const int* __restrict__ Sx, const int* __restrict__ bcnt,
    int2* __restrict__ epack, int* __restrict__ rowptr, int* __restrict__ cnt)
{
    __shared__ int hist[256], s[256], curs[256];
    const int b = blockIdx.x;
    const int base = Sx[b];
    const int cntE = bcnt[b];
    const int t = threadIdx.x;
    if (t < 256) hist[t] = 0;
    __syncthreads();
    for (int i = t; i < cntE; i += 512)
        atomicAdd(&hist[tmp_low[base + i]], 1);
    __syncthreads();
    if (t < 256) s[t] = hist[t];
    __syncthreads();
    #pragma unroll
    for (int off = 1; off < 256; off <<= 1) {
        const int add = (t < 256 && t >= off) ? s[t - off] : 0;
        __syncthreads();
        if (t < 256) s[t] += add;
        __syncthreads();
    }
    if (t < 256) {
        const int excl = s[t] - hist[t];
        curs[t] = excl;
        const int d = b * 256 + t;
        if (d < NN) { rowptr[d] = base + excl; cnt[d] = hist[t]; }
    }
    __syncthreads();
    for (int i = t; i < cntE; i += 512) {
        const int2 e = tmp_e[base + i];
        const int low = (int)tmp_low[base + i];
        const int pos = base + atomicAdd(&curs[low], 1);
        epack[pos] = e;
    }
}

// ---------------- fused layer: block = 16 nodes, 4 waves ---------------------
template<bool FINAL>
__global__ __launch_bounds__(256) void k_layer(
    const ushort* __restrict__ cur_in, ushort* __restrict__ cur_out,
    const int2* __restrict__ epack, const int* __restrict__ rowptr,
    const int* __restrict__ cnt,
    const ushort* __restrict__ WpL, const float* __restrict__ bvec,
    const float* __restrict__ temp,
    const ushort* __restrict__ hbf, const ushort* __restrict__ c1,
    const ushort* __restrict__ WpO, const float* __restrict__ bout,
    float* __restrict__ outp)
{
    __shared__ int2  es[4][64];
    __shared__ ushort ts[16][72];      // padded: bank-even b128 reads
    __shared__ float swv[16];          // per-node sum of edge weights (bias term)
    const int w = threadIdx.x >> 6;
    const int j = threadIdx.x & 63;
    const int nb = blockIdx.x * 16;

    // ---- gather-aggregate: wave w handles nodes nb + w*4 + q ----
    #pragma unroll
    for (int q = 0; q < 4; ++q) {
        const int n  = nb + w * 4 + q;
        const int rs = rowptr[n];
        const int rc = cnt[n];
        float acc = 0.0f;
        float sw  = 0.0f;
        for (int base = 0; base < rc; base += 64) {
            const int m = min(rc - base, 64);
            if (j < m) es[w][j] = epack[rs + base + j];
            for (int g = 0; g < m; g += 16) {
                float vv[16], ww[16];
                #pragma unroll
                for (int u = 0; u < 16; ++u) {
                    const int idx = g + u;
                    const int sel = (idx < m) ? idx : 0;   // clamp: dup line, cheap
                    const int2 p = es[w][sel];             // LDS broadcast read
                    ww[u] = (idx < m) ? __int_as_float(p.y) : 0.0f;
                    vv[u] = bf2f(cur_in[(size_t)p.x * HH + j]);
                }
                #pragma unroll
                for (int u = 0; u < 16; ++u) { acc = fmaf(ww[u], vv[u], acc); sw += ww[u]; }
            }
        }
        ts[w * 4 + q][j] = f2bf(acc);
        if (j == 0) swv[w * 4 + q] = sw;
    }
    __syncthreads();

    // ---- MFMA: wave w computes output cols [w*16, w*16+16) for 16 nodes ----
    const int lr = j & 15;             // within-tile col
    const int lg = j >> 4;             // reg group
    const short8 a0 = *(const short8*)&ts[lr][lg * 8];
    const short8 a1 = *(const short8*)&ts[lr][32 + lg * 8];
    if (FINAL) __syncthreads();        // all A-frags read before ts is reused

    const short8* WpV = (const short8*)WpL;
    f32x4 zac = {0,0,0,0};
    zac = __builtin_amdgcn_mfma_f32_16x16x32_bf16(a0, WpV[(w*2+0)*64 + j], zac, 0, 0, 0);
    zac = __builtin_amdgcn_mfma_f32_16x16x32_bf16(a1, WpV[(w*2+1)*64 + j], zac, 0, 0, 0);

    const float bb = bvec[w * 16 + lr];
    float t0v = 0, t1v = 0, t2v = 0, t3v = 0;
    if (FINAL) { t0v = temp[0]; t1v = temp[1]; t2v = temp[2]; t3v = temp[3]; }
    #pragma unroll
    for (int r = 0; r < 4; ++r) {
        const int row = lg * 4 + r;    // local node
        const int n   = nb + row;
        const float z = zac[r] + swv[row] * bb;
        const float rv = fmaxf(z, 0.0f);
        const size_t o = (size_t)n * HH + w * 16 + lr;
        if (!FINAL) {
            cur_out[o] = f2bf(rv);
        } else {
            const float hid = t0v * bf2f(hbf[o]) + t1v * bf2f(c1[o])
                            + t2v * bf2f(cur_in[o]) + t3v * rv;
            ts[row][w * 16 + lr] = f2bf(hid);
        }
    }
    if (FINAL) {
        __syncthreads();
        const short8 b0 = *(const short8*)&ts[lr][lg * 8];
        const short8 b1 = *(const short8*)&ts[lr][32 + lg * 8];
        const short8* WoV = (const short8*)WpO;
        f32x4 oz = {0,0,0,0};
        oz = __builtin_amdgcn_mfma_f32_16x16x32_bf16(b0, WoV[(w*2+0)*64 + j], oz, 0, 0, 0);
        oz = __builtin_amdgcn_mfma_f32_16x16x32_bf16(b1, WoV[(w*2+1)*64 + j], oz, 0, 0, 0);
        const float bo = bout[w * 16 + lr];
        #pragma unroll
        for (int r = 0; r < 4; ++r) {
            const int row = lg * 4 + r;
            outp[(size_t)(nb + row) * HH + w * 16 + lr] = oz[r] + bo;
        }
    }
}

extern "C" void kernel_launch(void* const* d_in, const int* in_sizes, int n_in,
                              void* d_out, int out_size, void* d_ws, size_t ws_size,
                              hipStream_t stream)
{
    const float* x     = (const float*)d_in[0];
    const int*   ei    = (const int*)d_in[1];
    const float* ew    = (const float*)d_in[2];
    const float* W_in  = (const float*)d_in[3];
    const float* b_in  = (const float*)d_in[4];
    const float* LW    = (const float*)d_in[5];
    const float* Lb    = (const float*)d_in[6];
    const float* W_out = (const float*)d_in[7];
    const float* b_out = (const float*)d_in[8];
    const float* temp  = (const float*)d_in[9];
    const int* src = ei;
    const int* dst = ei + NE;

    char* p = (char*)d_ws;
    ushort* h_bf    = (ushort*)p;  p += (size_t)NN * HH * 2;      // 6.4 MB
    ushort* curA    = (ushort*)p;  p += (size_t)NN * HH * 2;
    ushort* curB    = (ushort*)p;  p += (size_t)NN * HH * 2;
    int2*   epack   = (int2*)p;    p += (size_t)NE * 8;           // 6.4 MB
    int2*   tmp_e   = (int2*)p;    p += (size_t)NE * 8;           // 6.4 MB
    ushort* tmp_low = (ushort*)p;  p += (size_t)NE * 2;           // 1.6 MB
    int*    H       = (int*)p;     p += (size_t)NBINS * B1 * 4;   // 200 KB
    int*    Sx      = (int*)p;     p += (NBINS + 1) * 4;
    int*    bcnt    = (int*)p;     p += NBINS * 4;
    int*    rowptr  = (int*)p;     p += (size_t)NN * 4;
    int*    cnt     = (int*)p;     p += (size_t)NN * 4;
    ushort* Wp      = (ushort*)p;  p += 32768 * 2;                // 64 KB
    float*  out     = (float*)d_out;

    const ushort* WpIn  = Wp;
    const ushort* WpL0  = Wp + 16384;
    const ushort* WpL1  = Wp + 16384 + 4096;
    const ushort* WpL2  = Wp + 16384 + 2 * 4096;
    const ushort* WpOut = Wp + 16384 + 3 * 4096;

    // weights -> bf16 MFMA fragments
    k_prep<<<128, 256, 0, stream>>>(W_in, LW, W_out, Wp);
    // pass-A histogram (LDS only) fused with MFMA in-linear
    k_fused<<<B1 + NGB, 256, 0, stream>>>(x, WpIn, b_in, dst, H, h_bf);
    // global (bin,blk) offsets + bucket bases
    k_scanH<<<1, 256, 0, stream>>>(H, Sx, bcnt);
    // bucket placement (LDS cursors)
    k_scatterA<<<B1, 256, 0, stream>>>(src, dst, ew, H, tmp_e, tmp_low);
    // per-bucket LSD sort -> epack, rowptr, cnt
    k_sortB<<<NBINS, 512, 0, stream>>>(tmp_e, tmp_low, Sx, bcnt, epack, rowptr, cnt);

    // 3 fused propagation layers; FINAL recomputes hidden from bf16 terms
    k_layer<false><<<NLB, 256, 0, stream>>>(h_bf, curA, epack, rowptr, cnt,
                                            WpL0, Lb + 0 * HH, temp,
                                            nullptr, nullptr, nullptr, nullptr, nullptr);
    k_layer<false><<<NLB, 256, 0, stream>>>(curA, curB, epack, rowptr, cnt,
                                            WpL1, Lb + 1 * HH, temp,
                                            nullptr, nullptr, nullptr, nullptr, nullptr);
    k_layer<true><<<NLB, 256, 0, stream>>>(curB, nullptr, epack, rowptr, cnt,
                                           WpL2, Lb + 2 * HH, temp,
                                           h_bf, curA, WpOut, b_out, out);
}